// Round 9
// baseline (348.410 us; speedup 1.0000x reference)
//
#include <hip/hip_runtime.h>
#include <cstdio>

// Problem constants
constexpr int B_   = 2;
constexpr int S_   = 2048;
constexpr int D_   = 1024;
constexpr int H_   = 16;
constexpr int DFF_ = 4096;
constexpr int DK_  = D_ / H_;   // 64
constexpr int M_   = B_ * S_;   // 4096 tokens
constexpr float EPS_ = 1e-5f;
constexpr size_t MEGE = 1u << 20;          // 1M elems
constexpr size_t QKV_STRIDE = 4 * MEGE;    // Q->K->V slot stride (elems)
constexpr float QSCALE_ = 0.18033688011112042f;  // 0.125 * log2(e): folded into Q

typedef __attribute__((ext_vector_type(8))) short bf16x8;
typedef __attribute__((ext_vector_type(4))) float f32x4;

// ---------- bf16 helpers ----------
__device__ __forceinline__ float bf2f(unsigned int u) {
    return __uint_as_float(u << 16);
}
__device__ __forceinline__ unsigned short f2bf(float f) {          // RTNE
    unsigned int u = __float_as_uint(f);
    unsigned int r = u + 0x7fffu + ((u >> 16) & 1u);
    return (unsigned short)(r >> 16);
}
__device__ __forceinline__ unsigned short f2bf_rz(float f) {       // truncate (P matrix only)
    return (unsigned short)(__float_as_uint(f) >> 16);
}
// 2^x via native v_exp_f32 (NOT __exp2f — glibc macro collision; v_exp_f32 IS exp2).
__device__ __forceinline__ float exp2_fast(float x) {
    float r;
    asm("v_exp_f32 %0, %1" : "=v"(r) : "v"(x));
    return r;
}

// ---------- async global->LDS, 16B per lane ----------
__device__ __forceinline__ void gload_lds16(const unsigned short* g, unsigned short* l) {
    __builtin_amdgcn_global_load_lds(
        (const __attribute__((address_space(1))) unsigned int*)g,
        (__attribute__((address_space(3))) unsigned int*)l, 16, 0, 0);
}

// ---------- fused preprocessing: 6 weight transposes + x convert, ONE launch ----
__device__ __forceinline__ void tr32(const float* __restrict__ W, unsigned short* __restrict__ Wt,
                                     int K, int N, int bx, int by, float* t /*[32*33]*/)
{
    const int tx = threadIdx.x & 31, ty = threadIdx.x >> 5;   // 32 x 8
    const int n0 = bx * 32, k0 = by * 32;
    #pragma unroll
    for (int p = 0; p < 4; ++p)
        t[(ty + p * 8) * 33 + tx] = W[(size_t)(k0 + ty + p * 8) * N + n0 + tx];
    __syncthreads();
    #pragma unroll
    for (int p = 0; p < 4; ++p)
        Wt[(size_t)(n0 + ty + p * 8) * K + k0 + tx] = f2bf(t[tx * 33 + ty + p * 8]);
}

__global__ __launch_bounds__(256)
void prep_k(const float* __restrict__ wq, const float* __restrict__ wk,
            const float* __restrict__ wv, const float* __restrict__ wo,
            const float* __restrict__ w1, const float* __restrict__ w2,
            const float* __restrict__ x,
            unsigned short* __restrict__ wqt, unsigned short* __restrict__ wkt,
            unsigned short* __restrict__ wvt, unsigned short* __restrict__ wot,
            unsigned short* __restrict__ w1t, unsigned short* __restrict__ w2t,
            unsigned short* __restrict__ xb)
{
    __shared__ float t[32 * 33];
    const int bid = blockIdx.x;
    if (bid < 4096) {
        const int z = bid >> 10, rem = bid & 1023;
        const float* W = (z == 0) ? wq : (z == 1) ? wk : (z == 2) ? wv : wo;
        unsigned short* Wt = (z == 0) ? wqt : (z == 1) ? wkt : (z == 2) ? wvt : wot;
        tr32(W, Wt, D_, D_, rem & 31, rem >> 5, t);
    } else if (bid < 8192) {
        const int rem = bid - 4096;
        tr32(w1, w1t, D_, DFF_, rem & 127, rem >> 7, t);
    } else if (bid < 12288) {
        const int rem = bid - 8192;
        tr32(w2, w2t, DFF_, D_, rem & 31, rem >> 5, t);
    } else {
        const int i = (bid - 12288) * 256 + threadIdx.x;
        float4 f = reinterpret_cast<const float4*>(x)[i];
        ushort4 u;
        u.x = f2bf(f.x); u.y = f2bf(f.y); u.z = f2bf(f.z); u.w = f2bf(f.w);
        reinterpret_cast<ushort4*>(xb)[i] = u;
    }
}

// ---------- mg3: 16-wave 256x256 MFMA GEMM (QKV / FFN-up) ----------
template<int OMODE, bool RELU>
__global__ __launch_bounds__(1024, 1)
void mg3_k(const unsigned short* __restrict__ A,
           const unsigned short* __restrict__ Bt,
           const float* __restrict__ bias,
           unsigned short* __restrict__ C,
           int M, int N, int K, int Kld)
{
    __shared__ __align__(16) unsigned short As[2][256 * 64];
    __shared__ __align__(16) unsigned short Bs[2][256 * 64];

    const int tid = threadIdx.x;
    const int w = tid >> 6, lane = tid & 63;
    const int l15 = lane & 15, quad = lane >> 4;
    const int wm = w >> 2, wn = w & 3;              // 4M x 4N wave grid
    const int m0 = blockIdx.y * 256, n0 = blockIdx.x * 256;
    const int NT = K >> 6;

    const int srow = lane >> 3;                     // DMA row within 8-row group
    const int schk = (lane & 7) ^ srow;             // pre-swizzled source chunk
    const int rsw  = l15 & 7;                       // read-side swizzle key

    f32x4 acc[4][4];
    #pragma unroll
    for (int i = 0; i < 4; ++i)
        #pragma unroll
        for (int j = 0; j < 4; ++j) acc[i][j] = (f32x4){0.f, 0.f, 0.f, 0.f};

    auto stageAB = [&](int tile) {
        if (tile >= NT) return;
        const int buf = tile & 1;
        const int k0 = tile * 64;
        #pragma unroll
        for (int g = 0; g < 2; ++g) {
            const int r = w * 16 + g * 8;
            gload_lds16(A + (size_t)(m0 + r + srow) * Kld + k0 + schk * 8, &As[buf][r * 64]);
        }
        #pragma unroll
        for (int g = 0; g < 2; ++g) {
            const int r = w * 16 + g * 8;
            gload_lds16(Bt + (size_t)(n0 + r + srow) * Kld + k0 + schk * 8, &Bs[buf][r * 64]);
        }
    };

    bf16x8 a[4], b[4];
    auto rd = [&](int buf, int h) {
        #pragma unroll
        for (int i = 0; i < 4; ++i) {
            const unsigned short* rp = &As[buf][(wm * 64 + i * 16 + l15) * 64];
            a[i] = *reinterpret_cast<const bf16x8*>(rp + (((quad + 4 * h) ^ rsw) << 3));
        }
        #pragma unroll
        for (int j = 0; j < 4; ++j) {
            const unsigned short* rp = &Bs[buf][(wn * 64 + j * 16 + l15) * 64];
            b[j] = *reinterpret_cast<const bf16x8*>(rp + (((quad + 4 * h) ^ rsw) << 3));
        }
    };
    auto mm16 = [&]() {
        __builtin_amdgcn_s_setprio(1);
        #pragma unroll
        for (int i = 0; i < 4; ++i)
            #pragma unroll
            for (int j = 0; j < 4; ++j)
                acc[i][j] = __builtin_amdgcn_mfma_f32_16x16x32_bf16(a[i], b[j], acc[i][j], 0, 0, 0);
        __builtin_amdgcn_s_setprio(0);
    };

    stageAB(0);

    for (int t = 0; t < NT; ++t) {
        const int cur = t & 1;
        asm volatile("s_waitcnt vmcnt(0)" ::: "memory");  // drains tile t (issued 1 tile ago)
        __builtin_amdgcn_s_barrier();
        stageAB(t + 1);
        rd(cur, 0);
        __builtin_amdgcn_s_barrier();
        asm volatile("s_waitcnt lgkmcnt(0)" ::: "memory");
        mm16();
        rd(cur, 1);
        __builtin_amdgcn_s_barrier();
        asm volatile("s_waitcnt lgkmcnt(0)" ::: "memory");
        mm16();
    }

    #pragma unroll
    for (int i = 0; i < 4; ++i)
        #pragma unroll
        for (int r = 0; r < 4; ++r) {
            const int m = m0 + wm * 64 + i * 16 + quad * 4 + r;
            #pragma unroll
            for (int j = 0; j < 4; ++j) {
                const int n = n0 + wn * 64 + j * 16 + l15;
                float v = acc[i][j][r];
                if (bias) v += bias[n];
                if (RELU) v = fmaxf(v, 0.0f);
                size_t o;
                if (OMODE == 2) {
                    int mat = n >> 10, nn = n & 1023;
                    int bb = m >> 11, s = m & 2047;
                    int h = nn >> 6, dk = nn & 63;
                    if (mat == 0) v *= QSCALE_;   // fold softmax scale+log2e into Q
                    o = (size_t)mat * QKV_STRIDE + (((size_t)bb * H_ + h) * S_ + s) * DK_ + dk;
                } else {
                    o = (size_t)m * N + n;
                }
                C[o] = f2bf(v);
            }
        }
}

// ---------- phased MFMA GEMM (mg2, BM=128 path): Wo / FFN-down split-K ----------
template<int BM, int OMODE, bool RELU>
__global__ __launch_bounds__(512, 2)
void mg2_k(const unsigned short* __restrict__ A,
           const unsigned short* __restrict__ Bt,
           const float* __restrict__ bias,
           unsigned short* __restrict__ C,
           int M, int N, int K, int Kld)
{
    constexpr int MI  = BM / 64;
    constexpr int AMH = (BM == 128) ? 2 : 1;
    __shared__ __align__(16) unsigned short As[2][BM * 64];
    __shared__ __align__(16) unsigned short Bs[2][256 * 64];

    const int z = blockIdx.z;
    A  += (size_t)z * K;
    Bt += (size_t)z * K;
    C  += (size_t)z * ((size_t)M * N);

    const int tid  = threadIdx.x;
    const int w    = tid >> 6, lane = tid & 63;
    const int l15  = lane & 15, quad = lane >> 4;
    const int wm   = w >> 2, wn = w & 3;
    const int m0   = blockIdx.y * BM, n0 = blockIdx.x * 256;
    const int NT   = K >> 6;

    const int srow = lane >> 3;
    const int schk = (lane & 7) ^ srow;
    const int rsw  = l15 & 7;

    f32x4 acc[2][MI][2][2];
    #pragma unroll
    for (int mh = 0; mh < 2; ++mh)
        #pragma unroll
        for (int mi = 0; mi < MI; ++mi)
            #pragma unroll
            for (int nh = 0; nh < 2; ++nh)
                #pragma unroll
                for (int nj = 0; nj < 2; ++nj)
                    acc[mh][mi][nh][nj] = (f32x4){0.f, 0.f, 0.f, 0.f};

    bf16x8 aA[AMH][MI][2];
    bf16x8 b0[2][2], b1[2][2];

    auto stage = [&](int tile, int type) {
        if (tile >= NT) return;
        const int buf = tile & 1;
        unsigned short* dst; const unsigned short* src; int r0;
        if (BM == 256) {
            if      (type == 0) { dst = &As[buf][0];        src = A;  r0 = m0; }
            else if (type == 1) { dst = &Bs[buf][0];        src = Bt; r0 = n0; }
            else if (type == 2) { dst = &Bs[buf][128 * 64]; src = Bt; r0 = n0 + 128; }
            else                { dst = &As[buf][128 * 64]; src = A;  r0 = m0 + 128; }
        } else {
            if      (type == 0) { dst = &Bs[buf][0];        src = Bt; r0 = n0; }
            else if (type == 1) { dst = &As[buf][0];        src = A;  r0 = m0; }
            else                { dst = &Bs[buf][128 * 64]; src = Bt; r0 = n0 + 128; }
        }
        const int k0 = tile * 64;
        #pragma unroll
        for (int g = 0; g < 2; ++g) {
            const int r = w * 16 + g * 8 + srow;
            gload_lds16(src + (size_t)(r0 + r) * Kld + k0 + schk * 8,
                        dst + (w * 16 + g * 8) * 64);
        }
    };
    auto rdA = [&](int buf, int mh, int amh) {
        const unsigned short* base = &As[buf][(BM == 256 && mh) ? 128 * 64 : 0];
        #pragma unroll
        for (int mi = 0; mi < MI; ++mi) {
            const int row = (BM == 256) ? (wm * 64 + mi * 16 + l15)
                                        : (wm * 64 + mh * 32 + mi * 16 + l15);
            const unsigned short* rp = base + row * 64;
            aA[amh][mi][0] = *reinterpret_cast<const bf16x8*>(rp + ((quad    ) ^ rsw) * 8);
            aA[amh][mi][1] = *reinterpret_cast<const bf16x8*>(rp + ((quad + 4) ^ rsw) * 8);
        }
    };
    auto rdB = [&](int buf, int nh, bf16x8 (&b)[2][2]) {
        const unsigned short* base = &Bs[buf][nh ? 128 * 64 : 0];
        #pragma unroll
        for (int nj = 0; nj < 2; ++nj) {
            const int row = wn * 32 + nj * 16 + l15;
            const unsigned short* rp = base + row * 64;
            b[nj][0] = *reinterpret_cast<const bf16x8*>(rp + ((quad    ) ^ rsw) * 8);
            b[nj][1] = *reinterpret_cast<const bf16x8*>(rp + ((quad + 4) ^ rsw) * 8);
        }
    };
    auto mm = [&](int mh, int amh, int nh, bf16x8 (&b)[2][2]) {
        __builtin_amdgcn_s_setprio(1);
        #pragma unroll
        for (int mi = 0; mi < MI; ++mi)
            #pragma unroll
            for (int nj = 0; nj < 2; ++nj) {
                acc[mh][mi][nh][nj] = __builtin_amdgcn_mfma_f32_16x16x32_bf16(
                    aA[amh][mi][0], b[nj][0], acc[mh][mi][nh][nj], 0, 0, 0);
                acc[mh][mi][nh][nj] = __builtin_amdgcn_mfma_f32_16x16x32_bf16(
                    aA[amh][mi][1], b[nj][1], acc[mh][mi][nh][nj], 0, 0, 0);
            }
        __builtin_amdgcn_s_setprio(0);
    };

    if (BM == 256) {
        stage(0, 0); stage(0, 1); stage(0, 2); stage(0, 3);
        stage(1, 0); stage(1, 1); stage(1, 2);
    } else {
        stage(0, 0); stage(0, 1); stage(0, 2);
        stage(1, 0); stage(1, 1);
    }

    for (int t = 0; t < NT; ++t) {
        const int cur = t & 1;
        if (t == NT - 1)    asm volatile("s_waitcnt vmcnt(0)" ::: "memory");
        else if (BM == 256) asm volatile("s_waitcnt vmcnt(6)" ::: "memory");
        else                asm volatile("s_waitcnt vmcnt(4)" ::: "memory");
        __builtin_amdgcn_s_barrier();

        if (BM == 256) {
            rdA(cur, 0, 0); rdB(cur, 0, b0); stage(t + 1, 3);
            __builtin_amdgcn_s_barrier();
            asm volatile("s_waitcnt lgkmcnt(0)" ::: "memory");
            mm(0, 0, 0, b0);
            __builtin_amdgcn_s_barrier();
            rdB(cur, 1, b1); stage(t + 2, 0);
            __builtin_amdgcn_s_barrier();
            asm volatile("s_waitcnt lgkmcnt(0)" ::: "memory");
            mm(0, 0, 1, b1);
            __builtin_amdgcn_s_barrier();
            rdA(cur, 1, 0); stage(t + 2, 1);
            __builtin_amdgcn_s_barrier();
            asm volatile("s_waitcnt lgkmcnt(0)" ::: "memory");
            mm(1, 0, 0, b0);
            __builtin_amdgcn_s_barrier();
            stage(t + 2, 2);
            __builtin_amdgcn_s_barrier();
            asm volatile("s_waitcnt lgkmcnt(0)" ::: "memory");
            mm(1, 0, 1, b1);
        } else {
            rdA(cur, 0, 0); rdA(cur, 1, 1); rdB(cur, 0, b0); stage(t + 1, 2);
            __builtin_amdgcn_s_barrier();
            asm volatile("s_waitcnt lgkmcnt(0)" ::: "memory");
            mm(0, 0, 0, b0); mm(1, 1, 0, b0);
            __builtin_amdgcn_s_barrier();
            rdB(cur, 1, b1); stage(t + 2, 0); stage(t + 2, 1);
            __builtin_amdgcn_s_barrier();
            asm volatile("s_waitcnt lgkmcnt(0)" ::: "memory");
            mm(0, 0, 1, b1); mm(1, 1, 1, b1);
        }
    }

    #pragma unroll
    for (int mh = 0; mh < 2; ++mh)
        #pragma unroll
        for (int mi = 0; mi < MI; ++mi) {
            const int mrow = (BM == 256) ? (mh * 128 + wm * 64 + mi * 16)
                                         : (wm * 64 + mh * 32 + mi * 16);
            #pragma unroll
            for (int r = 0; r < 4; ++r) {
                const int m = m0 + mrow + quad * 4 + r;
                #pragma unroll
                for (int nh = 0; nh < 2; ++nh)
                    #pragma unroll
                    for (int nj = 0; nj < 2; ++nj) {
                        const int n = n0 + nh * 128 + wn * 32 + nj * 16 + l15;
                        float v = acc[mh][mi][nh][nj][r];
                        if (bias) v += bias[n];
                        if (RELU) v = fmaxf(v, 0.0f);
                        size_t o;
                        if (OMODE == 2) {
                            int mat = n >> 10, nn = n & 1023;
                            int b = m >> 11, s = m & 2047;
                            int h = nn >> 6, dk = nn & 63;
                            if (mat == 0) v *= QSCALE_;
                            o = (size_t)mat * QKV_STRIDE + (((size_t)b * H_ + h) * S_ + s) * DK_ + dk;
                        } else {
                            o = (size_t)m * N + n;
                        }
                        C[o] = f2bf(v);
                    }
            }
        }
}

// ---------- wave reduction ----------
__device__ __forceinline__ float wave_sum(float v) {
    #pragma unroll
    for (int off = 32; off > 0; off >>= 1) v += __shfl_down(v, off, 64);
    return v;
}

// ---------- flash attention v6: 4 waves x 32 q-rows, KV-split=2 ----------
// R8 post-mortem: v5 (8w x 16q) is LDS-read-byte-bound — all 8 waves duplicate
// the full K/V tile frag reads for only 16 q each. Per-q LDS bytes halve at
// 32 q/wave (R2-verified dataflow). Occupancy recovered via KV-split: this
// softmax has no running max, so partial (o, l) over disjoint KV halves
// combine LINEARLY: out = (oA+oB)/(lA+lB). blockIdx.y = kv half; grid 1024
// blocks -> 3 blocks/CU (LDS 53248x3 <= 160K) = 12 waves/CU. Blocks write
// unnormalized o (bf16) + l (f32) partials; comb_k does the combine.
constexpr int TQ_  = 128;
constexpr int TK_  = 64;
constexpr int NT2_ = (S_ / 2) / TK_;   // 16 kv tiles per half

__global__ __launch_bounds__(256, 3)
void fattn_k(const unsigned short* __restrict__ Qm, const unsigned short* __restrict__ Km,
             const unsigned short* __restrict__ Vm,
             unsigned short* __restrict__ Po0, unsigned short* __restrict__ Po1,
             float* __restrict__ Lp)
{
    const int bh  = blockIdx.x >> 4;     // 16 q-tiles per (b,h)
    const int qt  = blockIdx.x & 15;
    const int kvz = blockIdx.y;          // kv half
    const int tid = threadIdx.x;
    const int w = tid >> 6, lane = tid & 63;
    const int quad = lane >> 4, l15 = lane & 15;
    const int sw = l15 & 7;                          // read-side swizzle key

    __shared__ __align__(16) unsigned short Ks[2][TK_][64];   // K tile [kpos][d]
    __shared__ __align__(16) unsigned short Vt[2][80][64];    // V^T [d][col'] + ones rows 64..79
    __shared__ __align__(16) unsigned short Ps[4][32][64];    // per-wave P [q][col']

    // Q frags: wave w owns q rows qt*128 + w*32 + [0,32)
    bf16x8 qf[2][2];
    #pragma unroll
    for (int i = 0; i < 2; ++i) {
        const unsigned short* qp = Qm + ((size_t)bh * S_ + qt * TQ_ + w * 32 + i * 16 + l15) * DK_;
        qf[i][0] = *reinterpret_cast<const bf16x8*>(qp + quad * 8);
        qf[i][1] = *reinterpret_cast<const bf16x8*>(qp + 32 + quad * 8);
    }

    f32x4 o[2][4];
    f32x4 o4[2];
    #pragma unroll
    for (int i = 0; i < 2; ++i) {
        #pragma unroll
        for (int n = 0; n < 4; ++n) o[i][n] = (f32x4){0.f, 0.f, 0.f, 0.f};
        o4[i] = (f32x4){0.f, 0.f, 0.f, 0.f};
    }

    const unsigned short* kg0 = Km + (size_t)bh * S_ * DK_ + (size_t)kvz * (S_ / 2) * DK_;
    const unsigned short* vg0 = Vm + (size_t)bh * S_ * DK_ + (size_t)kvz * (S_ / 2) * DK_;
    const int dgrp = tid >> 4;     // 0..15: d-group of 4 dims
    const int vkp  = tid & 15;     // k-position low bits
    const int srow = lane >> 3;               // DMA: lane -> row within 8-row group
    const int schk = (lane & 7) ^ srow;       // pre-swizzled source chunk

    // K tile DMA: wave w stages rows [w*16, +16), linear dest, pre-swizzled src.
    auto stageK = [&](int t, int buf) {
        const unsigned short* src = kg0 + (size_t)t * TK_ * DK_;
        #pragma unroll
        for (int g = 0; g < 2; ++g) {
            const int r0 = w * 16 + g * 8;
            gload_lds16(src + (size_t)(r0 + srow) * DK_ + schk * 8, &Ks[buf][r0][0]);
        }
    };
    auto loadV = [&](int t, ushort4 (&vp)[4]) {
        const unsigned short* vg = vg0 + (size_t)t * TK_ * DK_;
        #pragma unroll
        for (int p = 0; p < 4; ++p)
            vp[p] = reinterpret_cast<const ushort4*>(vg + (size_t)(vkp + p * 16) * DK_)[dgrp];
    };
    auto storeVt = [&](int buf, ushort4 (&vp)[4]) {
        char* base = reinterpret_cast<char*>(&Vt[buf][dgrp * 4][0]);
        const int cs = vkp >> 1, ch = (vkp & 1) << 3;
        ushort4 pk;
        pk.x = vp[0].x; pk.y = vp[1].x; pk.z = vp[2].x; pk.w = vp[3].x;
        *reinterpret_cast<ushort4*>(base + 0 * 128 + (((cs ^ ((dgrp * 4 + 0) & 7)) << 4) + ch)) = pk;
        pk.x = vp[0].y; pk.y = vp[1].y; pk.z = vp[2].y; pk.w = vp[3].y;
        *reinterpret_cast<ushort4*>(base + 1 * 128 + (((cs ^ ((dgrp * 4 + 1) & 7)) << 4) + ch)) = pk;
        pk.x = vp[0].z; pk.y = vp[1].z; pk.z = vp[2].z; pk.w = vp[3].z;
        *reinterpret_cast<ushort4*>(base + 2 * 128 + (((cs ^ ((dgrp * 4 + 2) & 7)) << 4) + ch)) = pk;
        pk.x = vp[0].w; pk.y = vp[1].w; pk.z = vp[2].w; pk.w = vp[3].w;
        *reinterpret_cast<ushort4*>(base + 3 * 128 + (((cs ^ ((dgrp * 4 + 3) & 7)) << 4) + ch)) = pk;
    };

    // prologue: tile 0 staged; ones rows (denominator trick) init once
    stageK(0, 0);
    {
        ushort4 vp0[4];
        loadV(0, vp0);
        storeVt(0, vp0);
    }
    for (int idx = tid; idx < 2 * 16 * 64; idx += 256) {
        const int b  = idx >> 10;
        const int rr = (idx >> 6) & 15;
        const int cc = idx & 63;
        Vt[b][64 + rr][((cc >> 3) ^ (rr & 7)) * 8 + (cc & 7)] =
            (rr == 0) ? (unsigned short)0x3F80 : (unsigned short)0;
    }

    for (int t = 0; t < NT2_; ++t) {
        const int cur = t & 1, nxt = cur ^ 1;
        __syncthreads();   // vmcnt/lgkm drain + CU-wide LDS ordering

        const bool hn = (t + 1 < NT2_);
        ushort4 vp[4];
        if (hn) { stageK(t + 1, nxt); loadV(t + 1, vp); }

        // QK^T: 16 MFMA for 32 q-rows
        f32x4 s[2][4];
        __builtin_amdgcn_s_setprio(1);
        #pragma unroll
        for (int n = 0; n < 4; ++n) {
            const unsigned short* kp = &Ks[cur][n * 16 + l15][0];
            bf16x8 b0 = *reinterpret_cast<const bf16x8*>(kp + ((quad ^ sw) << 3));
            bf16x8 b1 = *reinterpret_cast<const bf16x8*>(kp + (((quad + 4) ^ sw) << 3));
            #pragma unroll
            for (int i = 0; i < 2; ++i) {
                f32x4 a2 = (f32x4){0.f, 0.f, 0.f, 0.f};
                a2 = __builtin_amdgcn_mfma_f32_16x16x32_bf16(qf[i][0], b0, a2, 0, 0, 0);
                a2 = __builtin_amdgcn_mfma_f32_16x16x32_bf16(qf[i][1], b1, a2, 0, 0, 0);
                s[i][n] = a2;
            }
        }
        __builtin_amdgcn_s_setprio(0);

        // softmax: P = exp2(s) (Q pre-scaled), write per-wave P tile
        #pragma unroll
        for (int i = 0; i < 2; ++i)
            #pragma unroll
            for (int r = 0; r < 4; ++r) {
                ushort4 pk;
                pk.x = f2bf_rz(exp2_fast(s[i][0][r]));
                pk.y = f2bf_rz(exp2_fast(s[i][1][r]));
                pk.z = f2bf_rz(exp2_fast(s[i][2][r]));
                pk.w = f2bf_rz(exp2_fast(s[i][3][r]));
                const int R = i * 16 + quad * 4 + r;
                *reinterpret_cast<ushort4*>(
                    reinterpret_cast<char*>(&Ps[w][R][0]) +
                    ((((l15 >> 1) ^ (R & 7)) << 4) + ((l15 & 1) << 3))) = pk;
            }

        if (hn) storeVt(nxt, vp);

        // PV: 20 MFMA
        bf16x8 pa[2][2];
        #pragma unroll
        for (int i = 0; i < 2; ++i) {
            const unsigned short* pp = &Ps[w][i * 16 + l15][0];
            pa[i][0] = *reinterpret_cast<const bf16x8*>(pp + ((quad ^ sw) << 3));
            pa[i][1] = *reinterpret_cast<const bf16x8*>(pp + (((quad + 4) ^ sw) << 3));
        }
        __builtin_amdgcn_s_setprio(1);
        #pragma unroll
        for (int n = 0; n < 4; ++n) {
            const unsigned short* vb = &Vt[cur][n * 16 + l15][0];
            bf16x8 vb0 = *reinterpret_cast<const bf16x8*>(vb + ((quad ^ sw) << 3));
            bf16x8 vb1 = *reinterpret_cast<const bf16x8*>(vb + (((quad + 4) ^ sw) << 3));
            #pragma unroll
            for (int i = 0; i < 2; ++i) {
                o[i][n] = __builtin_amdgcn_mfma_f32_16x16x32_bf16(pa[i][0], vb0, o[i][n], 0, 0, 0);
                o[i][n] = __builtin_amdgcn_mfma_f32_16x16x32_bf16(pa[i][1], vb1, o[i][n], 0, 0, 0);
            }
        }
        {
            const unsigned short* vb = &Vt[cur][64 + l15][0];
            bf16x8 vb40 = *reinterpret_cast<const bf16x8*>(vb + ((quad ^ sw) << 3));
            bf16x8 vb41 = *reinterpret_cast<const bf16x8*>(vb + (((quad + 4) ^ sw) << 3));
            #pragma unroll
            for (int i = 0; i < 2; ++i) {
                o4[i] = __builtin_amdgcn_mfma_f32_16x16x32_bf16(pa[i][0], vb40, o4[i], 0, 0, 0);
                o4[i] = __builtin_amdgcn_mfma_f32_16x16x32_bf16(pa[i][1], vb41, o4[i], 0, 0, 0);
            }
        }
        __builtin_amdgcn_s_setprio(0);
    }

    // epilogue: write UNNORMALIZED partial o (bf16) + partial l (f32)
    unsigned short* Po = kvz ? Po1 : Po0;
    const int b = bh >> 4, h = bh & 15;
    #pragma unroll
    for (int i = 0; i < 2; ++i)
        #pragma unroll
        for (int r = 0; r < 4; ++r) {
            float lrv = __shfl(o4[i][r], lane & 0x30, 64);   // l for row quad*4+r
            int q = qt * TQ_ + w * 32 + i * 16 + quad * 4 + r;
            if (l15 == 0) Lp[kvz * 65536 + bh * 2048 + q] = lrv;
            unsigned short* op = Po + ((size_t)b * S_ + q) * D_ + h * DK_;
            #pragma unroll
            for (int n = 0; n < 4; ++n)
                op[n * 16 + l15] = f2bf(o[i][n][r]);
        }
}

// ---------- combine: AO = (Po0 + Po1) / (L0 + L1) ----------
__global__ __launch_bounds__(256)
void comb_k(const unsigned short* __restrict__ Po0, const unsigned short* __restrict__ Po1,
            const float* __restrict__ Lp, unsigned short* __restrict__ AO)
{
    const size_t i4 = (size_t)blockIdx.x * 256 + threadIdx.x;
    const int e = (int)(i4 * 4);
    const int d = e & 1023, s = (e >> 10) & 2047, b = e >> 21;
    const int bh = b * 16 + (d >> 6);
    const float inv = 1.0f / (Lp[bh * 2048 + s] + Lp[65536 + bh * 2048 + s]);
    const ushort4 a = reinterpret_cast<const ushort4*>(Po0)[i4];
    const ushort4 c = reinterpret_cast<const ushort4*>(Po1)[i4];
    ushort4 u;
    u.x = f2bf((bf2f(a.x) + bf2f(c.x)) * inv);
    u.y = f2bf((bf2f(a.y) + bf2f(c.y)) * inv);
    u.z = f2bf((bf2f(a.z) + bf2f(c.z)) * inv);
    u.w = f2bf((bf2f(a.w) + bf2f(c.w)) * inv);
    reinterpret_cast<ushort4*>(AO)[i4] = u;
}

// ---------- reducing LayerNorm: v = P0+P1 (+bias) (+res), then LN (ddof=1) ----------
template<bool HAS_BIAS, bool RES_F32, bool OUT_F32>
__global__ __launch_bounds__(256)
void lnr_k(const unsigned short* __restrict__ P0, const unsigned short* __restrict__ P1,
           const void* __restrict__ res, const float* __restrict__ bias,
           const float* __restrict__ gp, const float* __restrict__ bp,
           void* __restrict__ Out)
{
    const int row = blockIdx.x;
    const int tid = threadIdx.x;
    const int lane = tid & 63, wave = tid >> 6;
    __shared__ float rs[4], rss[4];

    const size_t i4 = (size_t)row * 256 + tid;
    const ushort4 a = reinterpret_cast<const ushort4*>(P0)[i4];
    const ushort4 b = reinterpret_cast<const ushort4*>(P1)[i4];
    float v0 = bf2f(a.x) + bf2f(b.x);
    float v1 = bf2f(a.y) + bf2f(b.y);
    float v2 = bf2f(a.z) + bf2f(b.z);
    float v3 = bf2f(a.w) + bf2f(b.w);
    if (RES_F32) {
        float4 rv = reinterpret_cast<const float4*>(res)[i4];
        v0 += rv.x; v1 += rv.y; v2 += rv.z; v3 += rv.w;
    } else {
        ushort4 rv = reinterpret_cast<const ushort4*>(res)[i4];
        v0 += bf2f(rv.x); v1 += bf2f(rv.y); v2 += bf2f(rv.z); v3 += bf2f(rv.w);
    }
    if (HAS_BIAS) {
        float4 bv = reinterpret_cast<const float4*>(bias)[tid];
        v0 += bv.x; v1 += bv.y; v2 += bv.z; v3 += bv.w;
    }

    float s  = v0 + v1 + v2 + v3;
    float ss = v0*v0 + v1*v1 + v2*v2 + v3*v3;
    s = wave_sum(s);
    ss = wave_sum(ss);
    if (lane == 0) { rs[wave] = s; rss[wave] = ss; }
    __syncthreads();
    const float stot  = rs[0] + rs[1] + rs[2] + rs[3];
    const float sstot = rss[0] + rss[1] + rss[2] + rss[3];
    const float mean = stot / (float)D_;
    const float var  = (sstot - (float)D_ * mean * mean) / (float)(D_ - 1);
    const float scl = gp[0] * rsqrtf(var + EPS_);
    const float be = bp[0];

    float o0 = (v0 - mean) * scl + be;
    float o1 = (v1 - mean) * scl + be;
    float o2 = (v2 - mean) * scl + be;
    float o3 = (v3 - mean) * scl + be;
    if (OUT_F32) {
        reinterpret_cast<float4*>(Out)[i4] = make_float4(o0, o1, o2, o3);
    } else {
        ushort4 o;
        o.x = f2bf(o0); o.y = f2bf(o1); o.z = f2bf(o2); o.w = f2bf(o3);
        reinterpret_cast<ushort4*>(Out)[i4] = o;
    }
}

// ---------- host launch ----------
extern "C" void kernel_launch(void* const* d_in, const int* in_sizes, int n_in,
                              void* d_out, int out_size, void* d_ws, size_t ws_size,
                              hipStream_t stream)
{
    const float* x   = (const float*)d_in[0];
    const float* wq  = (const float*)d_in[2];
    const float* wk  = (const float*)d_in[3];
    const float* wv  = (const float*)d_in[4];
    const float* wo  = (const float*)d_in[5];
    const float* w1  = (const float*)d_in[6];
    const float* b1  = (const float*)d_in[7];
    const float* w2  = (const float*)d_in[8];
    const float* b2  = (const float*)d_in[9];
    const float* g1  = (const float*)d_in[10];
    const float* be1 = (const float*)d_in[11];
    const float* g2  = (const float*)d_in[12];
    const float* be2 = (const float*)d_in[13];

    unsigned short* ws = (unsigned short*)d_ws;
    const size_t need_bytes = 32 * MEGE * 2;           // 64 MB peak
    if (ws_size < need_bytes) {
        fprintf(stderr, "kernel_launch: ws too small (%zu < %zu)\n", ws_size, need_bytes);
    }
    // liveness: Lp (512KB f32) over dead wqt (slot 0-1) during attn;
    // Po0 over dead xb (slot 12-16); Po1 = AO slot (28-32), combined in place.
    unsigned short* wqt = ws + 0 * MEGE;
    unsigned short* wkt = ws + 1 * MEGE;
    unsigned short* wvt = ws + 2 * MEGE;
    unsigned short* wot = ws + 3 * MEGE;
    unsigned short* w1t = ws + 4 * MEGE;
    unsigned short* w2t = ws + 8 * MEGE;
    unsigned short* xb  = ws + 12 * MEGE;
    unsigned short* Q   = ws + 16 * MEGE;  // Q,K,V contiguous (QKV_STRIDE apart)
    unsigned short* K   = ws + 20 * MEGE;
    unsigned short* V   = ws + 24 * MEGE;
    unsigned short* AO  = ws + 28 * MEGE;
    unsigned short* Po0 = ws + 12 * MEGE;  // kv-half 0 partial (over dead xb)
    unsigned short* Po1 = ws + 28 * MEGE;  // kv-half 1 partial (= AO slot)
    float*          Lp  = (float*)ws;      // [2][32][2048] f32 over dead wqt
    unsigned short* x1  = xb;              // LN1 output (xb dead after QKV/combine)
    unsigned short* WP  = ws + 16 * MEGE;  // Wo split-K partials [2][M,D] over dead Q,K
    unsigned short* h1  = ws + 16 * MEGE;  // full [4096,4096] (after LN1)
    unsigned short* FP  = ws + 0 * MEGE;   // FFN-down partials [2][M,D] over dead wqt..w1t

    // 0) fused preprocessing: one launch (4 DxD + w1 + w2 transposes + x convert)
    prep_k<<<dim3(16384), 256, 0, stream>>>(wq, wk, wv, wo, w1, w2, x,
                                            wqt, wkt, wvt, wot, w1t, w2t, xb);

    // 1) fused QKV projection (Q pre-scaled): mg3 16-wave, 192 blocks x 1024 thr
    mg3_k<2, false><<<dim3(3 * D_ / 256, M_ / 256), 1024, 0, stream>>>(
        xb, wqt, nullptr, Q, M_, 3 * D_, D_, D_);

    // 2) flash attention, KV-split=2: 512x2 blocks x 256 thr (4 waves, 32 q each)
    fattn_k<<<dim3(B_ * H_ * (S_ / TQ_), 2), 256, 0, stream>>>(Q, K, V, Po0, Po1, Lp);

    // 2b) combine partials -> AO (in place over Po1)
    comb_k<<<dim3(B_ * S_ * D_ / 1024), 256, 0, stream>>>(Po0, Po1, Lp, AO);

    // 3) Wo split-K=2 (mg2 BM=128): 256 blocks, partials -> WP[2][M,D]
    mg2_k<128, 0, false><<<dim3(D_ / 256, M_ / 128, 2), 512, 0, stream>>>(
        AO, wot, nullptr, WP, M_, D_, D_ / 2, D_);

    // 4) LN1 = reduce(WP0+WP1) + x residual -> x1 (bf16)
    lnr_k<false, true, false><<<dim3(M_), 256, 0, stream>>>(
        WP, WP + 4 * MEGE, x, nullptr, g1, be1, x1);

    // 5) FFN-up: mg3 16-wave, 256 blocks x 1024 thr
    mg3_k<0, true><<<dim3(DFF_ / 256, M_ / 256), 1024, 0, stream>>>(
        x1, w1t, b1, h1, M_, DFF_, D_, D_);

    // 6) FFN-down split-K=2 (mg2 BM=128): 256 blocks, partials -> FP[2][M,D]
    mg2_k<128, 0, false><<<dim3(D_ / 256, M_ / 128, 2), 512, 0, stream>>>(
        h1, w2t, nullptr, FP, M_, D_, DFF_ / 2, DFF_);

    // 7) LN2 = reduce(FP0+FP1) + b2 + x1 residual -> fp32 output
    lnr_k<true, false, true><<<dim3(M_), 256, 0, stream>>>(
        FP, FP + 4 * MEGE, x1, b2, g2, be2, d_out);
}

// Round 10
// 335.386 us; speedup vs baseline: 1.0388x; 1.0388x over previous
//
#include <hip/hip_runtime.h>
#include <cstdio>

// Problem constants
constexpr int B_   = 2;
constexpr int S_   = 2048;
constexpr int D_   = 1024;
constexpr int H_   = 16;
constexpr int DFF_ = 4096;
constexpr int DK_  = D_ / H_;   // 64
constexpr int M_   = B_ * S_;   // 4096 tokens
constexpr float EPS_ = 1e-5f;
constexpr size_t MEGE = 1u << 20;          // 1M elems
constexpr size_t QKV_STRIDE = 4 * MEGE;    // Q->K->V slot stride (elems)
constexpr float QSCALE_ = 0.18033688011112042f;  // 0.125 * log2(e): folded into Q

typedef __attribute__((ext_vector_type(8))) short bf16x8;
typedef __attribute__((ext_vector_type(4))) float f32x4;

// ---------- bf16 helpers ----------
__device__ __forceinline__ float bf2f(unsigned int u) {
    return __uint_as_float(u << 16);
}
__device__ __forceinline__ unsigned short f2bf(float f) {          // RTNE
    unsigned int u = __float_as_uint(f);
    unsigned int r = u + 0x7fffu + ((u >> 16) & 1u);
    return (unsigned short)(r >> 16);
}
__device__ __forceinline__ unsigned short f2bf_rz(float f) {       // truncate (P matrix only)
    return (unsigned short)(__float_as_uint(f) >> 16);
}
// 2^x via native v_exp_f32 (NOT __exp2f — glibc macro collision; v_exp_f32 IS exp2).
__device__ __forceinline__ float exp2_fast(float x) {
    float r;
    asm("v_exp_f32 %0, %1" : "=v"(r) : "v"(x));
    return r;
}

// ---------- async global->LDS, 16B per lane ----------
__device__ __forceinline__ void gload_lds16(const unsigned short* g, unsigned short* l) {
    __builtin_amdgcn_global_load_lds(
        (const __attribute__((address_space(1))) unsigned int*)g,
        (__attribute__((address_space(3))) unsigned int*)l, 16, 0, 0);
}

// ---------- fused preprocessing: 6 weight transposes + x convert, ONE launch ----
__device__ __forceinline__ void tr32(const float* __restrict__ W, unsigned short* __restrict__ Wt,
                                     int K, int N, int bx, int by, float* t /*[32*33]*/)
{
    const int tx = threadIdx.x & 31, ty = threadIdx.x >> 5;   // 32 x 8
    const int n0 = bx * 32, k0 = by * 32;
    #pragma unroll
    for (int p = 0; p < 4; ++p)
        t[(ty + p * 8) * 33 + tx] = W[(size_t)(k0 + ty + p * 8) * N + n0 + tx];
    __syncthreads();
    #pragma unroll
    for (int p = 0; p < 4; ++p)
        Wt[(size_t)(n0 + ty + p * 8) * K + k0 + tx] = f2bf(t[tx * 33 + ty + p * 8]);
}

__global__ __launch_bounds__(256)
void prep_k(const float* __restrict__ wq, const float* __restrict__ wk,
            const float* __restrict__ wv, const float* __restrict__ wo,
            const float* __restrict__ w1, const float* __restrict__ w2,
            const float* __restrict__ x,
            unsigned short* __restrict__ wqt, unsigned short* __restrict__ wkt,
            unsigned short* __restrict__ wvt, unsigned short* __restrict__ wot,
            unsigned short* __restrict__ w1t, unsigned short* __restrict__ w2t,
            unsigned short* __restrict__ xb)
{
    __shared__ float t[32 * 33];
    const int bid = blockIdx.x;
    if (bid < 4096) {
        const int z = bid >> 10, rem = bid & 1023;
        const float* W = (z == 0) ? wq : (z == 1) ? wk : (z == 2) ? wv : wo;
        unsigned short* Wt = (z == 0) ? wqt : (z == 1) ? wkt : (z == 2) ? wvt : wot;
        tr32(W, Wt, D_, D_, rem & 31, rem >> 5, t);
    } else if (bid < 8192) {
        const int rem = bid - 4096;
        tr32(w1, w1t, D_, DFF_, rem & 127, rem >> 7, t);
    } else if (bid < 12288) {
        const int rem = bid - 8192;
        tr32(w2, w2t, DFF_, D_, rem & 31, rem >> 5, t);
    } else {
        const int i = (bid - 12288) * 256 + threadIdx.x;
        float4 f = reinterpret_cast<const float4*>(x)[i];
        ushort4 u;
        u.x = f2bf(f.x); u.y = f2bf(f.y); u.z = f2bf(f.z); u.w = f2bf(f.w);
        reinterpret_cast<ushort4*>(xb)[i] = u;
    }
}

// ---------- mg3: 16-wave 256x256 MFMA GEMM (QKV / FFN-up) ----------
template<int OMODE, bool RELU>
__global__ __launch_bounds__(1024, 1)
void mg3_k(const unsigned short* __restrict__ A,
           const unsigned short* __restrict__ Bt,
           const float* __restrict__ bias,
           unsigned short* __restrict__ C,
           int M, int N, int K, int Kld)
{
    __shared__ __align__(16) unsigned short As[2][256 * 64];
    __shared__ __align__(16) unsigned short Bs[2][256 * 64];

    const int tid = threadIdx.x;
    const int w = tid >> 6, lane = tid & 63;
    const int l15 = lane & 15, quad = lane >> 4;
    const int wm = w >> 2, wn = w & 3;              // 4M x 4N wave grid
    const int m0 = blockIdx.y * 256, n0 = blockIdx.x * 256;
    const int NT = K >> 6;

    const int srow = lane >> 3;                     // DMA row within 8-row group
    const int schk = (lane & 7) ^ srow;             // pre-swizzled source chunk
    const int rsw  = l15 & 7;                       // read-side swizzle key

    f32x4 acc[4][4];
    #pragma unroll
    for (int i = 0; i < 4; ++i)
        #pragma unroll
        for (int j = 0; j < 4; ++j) acc[i][j] = (f32x4){0.f, 0.f, 0.f, 0.f};

    auto stageAB = [&](int tile) {
        if (tile >= NT) return;
        const int buf = tile & 1;
        const int k0 = tile * 64;
        #pragma unroll
        for (int g = 0; g < 2; ++g) {
            const int r = w * 16 + g * 8;
            gload_lds16(A + (size_t)(m0 + r + srow) * Kld + k0 + schk * 8, &As[buf][r * 64]);
        }
        #pragma unroll
        for (int g = 0; g < 2; ++g) {
            const int r = w * 16 + g * 8;
            gload_lds16(Bt + (size_t)(n0 + r + srow) * Kld + k0 + schk * 8, &Bs[buf][r * 64]);
        }
    };

    bf16x8 a[4], b[4];
    auto rd = [&](int buf, int h) {
        #pragma unroll
        for (int i = 0; i < 4; ++i) {
            const unsigned short* rp = &As[buf][(wm * 64 + i * 16 + l15) * 64];
            a[i] = *reinterpret_cast<const bf16x8*>(rp + (((quad + 4 * h) ^ rsw) << 3));
        }
        #pragma unroll
        for (int j = 0; j < 4; ++j) {
            const unsigned short* rp = &Bs[buf][(wn * 64 + j * 16 + l15) * 64];
            b[j] = *reinterpret_cast<const bf16x8*>(rp + (((quad + 4 * h) ^ rsw) << 3));
        }
    };
    auto mm16 = [&]() {
        __builtin_amdgcn_s_setprio(1);
        #pragma unroll
        for (int i = 0; i < 4; ++i)
            #pragma unroll
            for (int j = 0; j < 4; ++j)
                acc[i][j] = __builtin_amdgcn_mfma_f32_16x16x32_bf16(a[i], b[j], acc[i][j], 0, 0, 0);
        __builtin_amdgcn_s_setprio(0);
    };

    stageAB(0);

    for (int t = 0; t < NT; ++t) {
        const int cur = t & 1;
        asm volatile("s_waitcnt vmcnt(0)" ::: "memory");  // drains tile t (issued 1 tile ago)
        __builtin_amdgcn_s_barrier();
        stageAB(t + 1);
        rd(cur, 0);
        __builtin_amdgcn_s_barrier();
        asm volatile("s_waitcnt lgkmcnt(0)" ::: "memory");
        mm16();
        rd(cur, 1);
        __builtin_amdgcn_s_barrier();
        asm volatile("s_waitcnt lgkmcnt(0)" ::: "memory");
        mm16();
    }

    #pragma unroll
    for (int i = 0; i < 4; ++i)
        #pragma unroll
        for (int r = 0; r < 4; ++r) {
            const int m = m0 + wm * 64 + i * 16 + quad * 4 + r;
            #pragma unroll
            for (int j = 0; j < 4; ++j) {
                const int n = n0 + wn * 64 + j * 16 + l15;
                float v = acc[i][j][r];
                if (bias) v += bias[n];
                if (RELU) v = fmaxf(v, 0.0f);
                size_t o;
                if (OMODE == 2) {
                    int mat = n >> 10, nn = n & 1023;
                    int bb = m >> 11, s = m & 2047;
                    int h = nn >> 6, dk = nn & 63;
                    if (mat == 0) v *= QSCALE_;   // fold softmax scale+log2e into Q
                    o = (size_t)mat * QKV_STRIDE + (((size_t)bb * H_ + h) * S_ + s) * DK_ + dk;
                } else {
                    o = (size_t)m * N + n;
                }
                C[o] = f2bf(v);
            }
        }
}

// ---------- phased MFMA GEMM (mg2, BM=128 path): Wo / FFN-down split-K ----------
template<int BM, int OMODE, bool RELU>
__global__ __launch_bounds__(512, 2)
void mg2_k(const unsigned short* __restrict__ A,
           const unsigned short* __restrict__ Bt,
           const float* __restrict__ bias,
           unsigned short* __restrict__ C,
           int M, int N, int K, int Kld)
{
    constexpr int MI  = BM / 64;
    constexpr int AMH = (BM == 128) ? 2 : 1;
    __shared__ __align__(16) unsigned short As[2][BM * 64];
    __shared__ __align__(16) unsigned short Bs[2][256 * 64];

    const int z = blockIdx.z;
    A  += (size_t)z * K;
    Bt += (size_t)z * K;
    C  += (size_t)z * ((size_t)M * N);

    const int tid  = threadIdx.x;
    const int w    = tid >> 6, lane = tid & 63;
    const int l15  = lane & 15, quad = lane >> 4;
    const int wm   = w >> 2, wn = w & 3;
    const int m0   = blockIdx.y * BM, n0 = blockIdx.x * 256;
    const int NT   = K >> 6;

    const int srow = lane >> 3;
    const int schk = (lane & 7) ^ srow;
    const int rsw  = l15 & 7;

    f32x4 acc[2][MI][2][2];
    #pragma unroll
    for (int mh = 0; mh < 2; ++mh)
        #pragma unroll
        for (int mi = 0; mi < MI; ++mi)
            #pragma unroll
            for (int nh = 0; nh < 2; ++nh)
                #pragma unroll
                for (int nj = 0; nj < 2; ++nj)
                    acc[mh][mi][nh][nj] = (f32x4){0.f, 0.f, 0.f, 0.f};

    bf16x8 aA[AMH][MI][2];
    bf16x8 b0[2][2], b1[2][2];

    auto stage = [&](int tile, int type) {
        if (tile >= NT) return;
        const int buf = tile & 1;
        unsigned short* dst; const unsigned short* src; int r0;
        if (BM == 256) {
            if      (type == 0) { dst = &As[buf][0];        src = A;  r0 = m0; }
            else if (type == 1) { dst = &Bs[buf][0];        src = Bt; r0 = n0; }
            else if (type == 2) { dst = &Bs[buf][128 * 64]; src = Bt; r0 = n0 + 128; }
            else                { dst = &As[buf][128 * 64]; src = A;  r0 = m0 + 128; }
        } else {
            if      (type == 0) { dst = &Bs[buf][0];        src = Bt; r0 = n0; }
            else if (type == 1) { dst = &As[buf][0];        src = A;  r0 = m0; }
            else                { dst = &Bs[buf][128 * 64]; src = Bt; r0 = n0 + 128; }
        }
        const int k0 = tile * 64;
        #pragma unroll
        for (int g = 0; g < 2; ++g) {
            const int r = w * 16 + g * 8 + srow;
            gload_lds16(src + (size_t)(r0 + r) * Kld + k0 + schk * 8,
                        dst + (w * 16 + g * 8) * 64);
        }
    };
    auto rdA = [&](int buf, int mh, int amh) {
        const unsigned short* base = &As[buf][(BM == 256 && mh) ? 128 * 64 : 0];
        #pragma unroll
        for (int mi = 0; mi < MI; ++mi) {
            const int row = (BM == 256) ? (wm * 64 + mi * 16 + l15)
                                        : (wm * 64 + mh * 32 + mi * 16 + l15);
            const unsigned short* rp = base + row * 64;
            aA[amh][mi][0] = *reinterpret_cast<const bf16x8*>(rp + ((quad    ) ^ rsw) * 8);
            aA[amh][mi][1] = *reinterpret_cast<const bf16x8*>(rp + ((quad + 4) ^ rsw) * 8);
        }
    };
    auto rdB = [&](int buf, int nh, bf16x8 (&b)[2][2]) {
        const unsigned short* base = &Bs[buf][nh ? 128 * 64 : 0];
        #pragma unroll
        for (int nj = 0; nj < 2; ++nj) {
            const int row = wn * 32 + nj * 16 + l15;
            const unsigned short* rp = base + row * 64;
            b[nj][0] = *reinterpret_cast<const bf16x8*>(rp + ((quad    ) ^ rsw) * 8);
            b[nj][1] = *reinterpret_cast<const bf16x8*>(rp + ((quad + 4) ^ rsw) * 8);
        }
    };
    auto mm = [&](int mh, int amh, int nh, bf16x8 (&b)[2][2]) {
        __builtin_amdgcn_s_setprio(1);
        #pragma unroll
        for (int mi = 0; mi < MI; ++mi)
            #pragma unroll
            for (int nj = 0; nj < 2; ++nj) {
                acc[mh][mi][nh][nj] = __builtin_amdgcn_mfma_f32_16x16x32_bf16(
                    aA[amh][mi][0], b[nj][0], acc[mh][mi][nh][nj], 0, 0, 0);
                acc[mh][mi][nh][nj] = __builtin_amdgcn_mfma_f32_16x16x32_bf16(
                    aA[amh][mi][1], b[nj][1], acc[mh][mi][nh][nj], 0, 0, 0);
            }
        __builtin_amdgcn_s_setprio(0);
    };

    if (BM == 256) {
        stage(0, 0); stage(0, 1); stage(0, 2); stage(0, 3);
        stage(1, 0); stage(1, 1); stage(1, 2);
    } else {
        stage(0, 0); stage(0, 1); stage(0, 2);
        stage(1, 0); stage(1, 1);
    }

    for (int t = 0; t < NT; ++t) {
        const int cur = t & 1;
        if (t == NT - 1)    asm volatile("s_waitcnt vmcnt(0)" ::: "memory");
        else if (BM == 256) asm volatile("s_waitcnt vmcnt(6)" ::: "memory");
        else                asm volatile("s_waitcnt vmcnt(4)" ::: "memory");
        __builtin_amdgcn_s_barrier();

        if (BM == 256) {
            rdA(cur, 0, 0); rdB(cur, 0, b0); stage(t + 1, 3);
            __builtin_amdgcn_s_barrier();
            asm volatile("s_waitcnt lgkmcnt(0)" ::: "memory");
            mm(0, 0, 0, b0);
            __builtin_amdgcn_s_barrier();
            rdB(cur, 1, b1); stage(t + 2, 0);
            __builtin_amdgcn_s_barrier();
            asm volatile("s_waitcnt lgkmcnt(0)" ::: "memory");
            mm(0, 0, 1, b1);
            __builtin_amdgcn_s_barrier();
            rdA(cur, 1, 0); stage(t + 2, 1);
            __builtin_amdgcn_s_barrier();
            asm volatile("s_waitcnt lgkmcnt(0)" ::: "memory");
            mm(1, 0, 0, b0);
            __builtin_amdgcn_s_barrier();
            stage(t + 2, 2);
            __builtin_amdgcn_s_barrier();
            asm volatile("s_waitcnt lgkmcnt(0)" ::: "memory");
            mm(1, 0, 1, b1);
        } else {
            rdA(cur, 0, 0); rdA(cur, 1, 1); rdB(cur, 0, b0); stage(t + 1, 2);
            __builtin_amdgcn_s_barrier();
            asm volatile("s_waitcnt lgkmcnt(0)" ::: "memory");
            mm(0, 0, 0, b0); mm(1, 1, 0, b0);
            __builtin_amdgcn_s_barrier();
            rdB(cur, 1, b1); stage(t + 2, 0); stage(t + 2, 1);
            __builtin_amdgcn_s_barrier();
            asm volatile("s_waitcnt lgkmcnt(0)" ::: "memory");
            mm(0, 0, 1, b1); mm(1, 1, 1, b1);
        }
    }

    #pragma unroll
    for (int mh = 0; mh < 2; ++mh)
        #pragma unroll
        for (int mi = 0; mi < MI; ++mi) {
            const int mrow = (BM == 256) ? (mh * 128 + wm * 64 + mi * 16)
                                         : (wm * 64 + mh * 32 + mi * 16);
            #pragma unroll
            for (int r = 0; r < 4; ++r) {
                const int m = m0 + mrow + quad * 4 + r;
                #pragma unroll
                for (int nh = 0; nh < 2; ++nh)
                    #pragma unroll
                    for (int nj = 0; nj < 2; ++nj) {
                        const int n = n0 + nh * 128 + wn * 32 + nj * 16 + l15;
                        float v = acc[mh][mi][nh][nj][r];
                        if (bias) v += bias[n];
                        if (RELU) v = fmaxf(v, 0.0f);
                        size_t o;
                        if (OMODE == 2) {
                            int mat = n >> 10, nn = n & 1023;
                            int b = m >> 11, s = m & 2047;
                            int h = nn >> 6, dk = nn & 63;
                            if (mat == 0) v *= QSCALE_;
                            o = (size_t)mat * QKV_STRIDE + (((size_t)b * H_ + h) * S_ + s) * DK_ + dk;
                        } else {
                            o = (size_t)m * N + n;
                        }
                        C[o] = f2bf(v);
                    }
            }
        }
}

// ---------- wave reduction ----------
__device__ __forceinline__ float wave_sum(float v) {
    #pragma unroll
    for (int off = 32; off > 0; off >>= 1) v += __shfl_down(v, off, 64);
    return v;
}

// ---------- flash attention v7: 4 waves x 32 q, KV-split=2, 40KB LDS ----------
// R9 post-mortem: v6's 52KB LDS never reached 3 blocks/CU (occ 20.8%), and the
// 4-per-CU grid with 3-resident would tail anyway. v7: LDS = exactly 40960 B
// (Ks 16K + Vt[2][64][64] 16K + Ps[4][16][64] 8K) -> 4 blocks/CU co-resident,
// grid = exactly 4/CU, one round, 16 waves/CU of 32q-waves (2x less LDS
// traffic per q than v5). Denominator via register accumulation + one 16-lane
// shfl_xor butterfly at epilogue (ones-rows + 4 MFMA/tile removed). Ps is a
// single 16-row half-buffer reused for both halves (per-wave in-order DS pipe
// + compiler aliasing order write-h0 -> read-pa0 -> write-h1 -> read-pa1).
constexpr int TQ_  = 128;
constexpr int TK_  = 64;
constexpr int NT2_ = (S_ / 2) / TK_;   // 16 kv tiles per half

__global__ __launch_bounds__(256, 4)
void fattn_k(const unsigned short* __restrict__ Qm, const unsigned short* __restrict__ Km,
             const unsigned short* __restrict__ Vm,
             unsigned short* __restrict__ Po0, unsigned short* __restrict__ Po1,
             float* __restrict__ Lp)
{
    const int bh  = blockIdx.x >> 4;     // 16 q-tiles per (b,h)
    const int qt  = blockIdx.x & 15;
    const int kvz = blockIdx.y;          // kv half
    const int tid = threadIdx.x;
    const int w = tid >> 6, lane = tid & 63;
    const int quad = lane >> 4, l15 = lane & 15;
    const int sw = l15 & 7;                          // read-side swizzle key

    __shared__ __align__(16) unsigned short Ks[2][TK_][64];   // 16 KB
    __shared__ __align__(16) unsigned short Vt[2][64][64];    // 16 KB (V^T)
    __shared__ __align__(16) unsigned short Ps[4][16][64];    // 8 KB (half-buffer)

    // Q frags: wave w owns q rows qt*128 + w*32 + [0,32)
    bf16x8 qf[2][2];
    #pragma unroll
    for (int i = 0; i < 2; ++i) {
        const unsigned short* qp = Qm + ((size_t)bh * S_ + qt * TQ_ + w * 32 + i * 16 + l15) * DK_;
        qf[i][0] = *reinterpret_cast<const bf16x8*>(qp + quad * 8);
        qf[i][1] = *reinterpret_cast<const bf16x8*>(qp + 32 + quad * 8);
    }

    f32x4 o[2][4];
    float lacc[2][4];
    #pragma unroll
    for (int i = 0; i < 2; ++i) {
        #pragma unroll
        for (int n = 0; n < 4; ++n) o[i][n] = (f32x4){0.f, 0.f, 0.f, 0.f};
        #pragma unroll
        for (int r = 0; r < 4; ++r) lacc[i][r] = 0.f;
    }

    const unsigned short* kg0 = Km + (size_t)bh * S_ * DK_ + (size_t)kvz * (S_ / 2) * DK_;
    const unsigned short* vg0 = Vm + (size_t)bh * S_ * DK_ + (size_t)kvz * (S_ / 2) * DK_;
    const int dgrp = tid >> 4;     // 0..15: d-group of 4 dims
    const int vkp  = tid & 15;     // k-position low bits
    const int srow = lane >> 3;               // DMA: lane -> row within 8-row group
    const int schk = (lane & 7) ^ srow;       // pre-swizzled source chunk

    auto stageK = [&](int t, int buf) {
        const unsigned short* src = kg0 + (size_t)t * TK_ * DK_;
        #pragma unroll
        for (int g = 0; g < 2; ++g) {
            const int r0 = w * 16 + g * 8;
            gload_lds16(src + (size_t)(r0 + srow) * DK_ + schk * 8, &Ks[buf][r0][0]);
        }
    };
    auto loadV = [&](int t, ushort4 (&vp)[4]) {
        const unsigned short* vg = vg0 + (size_t)t * TK_ * DK_;
        #pragma unroll
        for (int p = 0; p < 4; ++p)
            vp[p] = reinterpret_cast<const ushort4*>(vg + (size_t)(vkp + p * 16) * DK_)[dgrp];
    };
    auto storeVt = [&](int buf, ushort4 (&vp)[4]) {
        char* base = reinterpret_cast<char*>(&Vt[buf][dgrp * 4][0]);
        const int cs = vkp >> 1, ch = (vkp & 1) << 3;
        ushort4 pk;
        pk.x = vp[0].x; pk.y = vp[1].x; pk.z = vp[2].x; pk.w = vp[3].x;
        *reinterpret_cast<ushort4*>(base + 0 * 128 + (((cs ^ ((dgrp * 4 + 0) & 7)) << 4) + ch)) = pk;
        pk.x = vp[0].y; pk.y = vp[1].y; pk.z = vp[2].y; pk.w = vp[3].y;
        *reinterpret_cast<ushort4*>(base + 1 * 128 + (((cs ^ ((dgrp * 4 + 1) & 7)) << 4) + ch)) = pk;
        pk.x = vp[0].z; pk.y = vp[1].z; pk.z = vp[2].z; pk.w = vp[3].z;
        *reinterpret_cast<ushort4*>(base + 2 * 128 + (((cs ^ ((dgrp * 4 + 2) & 7)) << 4) + ch)) = pk;
        pk.x = vp[0].w; pk.y = vp[1].w; pk.z = vp[2].w; pk.w = vp[3].w;
        *reinterpret_cast<ushort4*>(base + 3 * 128 + (((cs ^ ((dgrp * 4 + 3) & 7)) << 4) + ch)) = pk;
    };

    // prologue: tile 0 staged
    stageK(0, 0);
    {
        ushort4 vp0[4];
        loadV(0, vp0);
        storeVt(0, vp0);
    }

    for (int t = 0; t < NT2_; ++t) {
        const int cur = t & 1, nxt = cur ^ 1;
        __syncthreads();   // vmcnt/lgkm drain + CU-wide LDS ordering

        const bool hn = (t + 1 < NT2_);
        ushort4 vp[4];
        if (hn) { stageK(t + 1, nxt); loadV(t + 1, vp); }

        // QK^T: 16 MFMA for 32 q-rows
        f32x4 s[2][4];
        __builtin_amdgcn_s_setprio(1);
        #pragma unroll
        for (int n = 0; n < 4; ++n) {
            const unsigned short* kp = &Ks[cur][n * 16 + l15][0];
            bf16x8 b0 = *reinterpret_cast<const bf16x8*>(kp + ((quad ^ sw) << 3));
            bf16x8 b1 = *reinterpret_cast<const bf16x8*>(kp + (((quad + 4) ^ sw) << 3));
            #pragma unroll
            for (int i = 0; i < 2; ++i) {
                f32x4 a2 = (f32x4){0.f, 0.f, 0.f, 0.f};
                a2 = __builtin_amdgcn_mfma_f32_16x16x32_bf16(qf[i][0], b0, a2, 0, 0, 0);
                a2 = __builtin_amdgcn_mfma_f32_16x16x32_bf16(qf[i][1], b1, a2, 0, 0, 0);
                s[i][n] = a2;
            }
        }
        __builtin_amdgcn_s_setprio(0);

        // softmax halves: exp + l-accumulate + P write + pa read (Ps reused)
        bf16x8 pa[2][2];
        #pragma unroll
        for (int i = 0; i < 2; ++i) {
            #pragma unroll
            for (int r = 0; r < 4; ++r) {
                float p0 = exp2_fast(s[i][0][r]);
                float p1 = exp2_fast(s[i][1][r]);
                float p2 = exp2_fast(s[i][2][r]);
                float p3 = exp2_fast(s[i][3][r]);
                lacc[i][r] += (p0 + p1) + (p2 + p3);
                ushort4 pk;
                pk.x = f2bf_rz(p0); pk.y = f2bf_rz(p1);
                pk.z = f2bf_rz(p2); pk.w = f2bf_rz(p3);
                const int R = quad * 4 + r;
                *reinterpret_cast<ushort4*>(
                    reinterpret_cast<char*>(&Ps[w][R][0]) +
                    ((((l15 >> 1) ^ (R & 7)) << 4) + ((l15 & 1) << 3))) = pk;
            }
            const unsigned short* pp = &Ps[w][l15][0];
            pa[i][0] = *reinterpret_cast<const bf16x8*>(pp + ((quad ^ sw) << 3));
            pa[i][1] = *reinterpret_cast<const bf16x8*>(pp + (((quad + 4) ^ sw) << 3));
        }

        if (hn) storeVt(nxt, vp);

        // PV: 16 MFMA
        __builtin_amdgcn_s_setprio(1);
        #pragma unroll
        for (int n = 0; n < 4; ++n) {
            const unsigned short* vb = &Vt[cur][n * 16 + l15][0];
            bf16x8 vb0 = *reinterpret_cast<const bf16x8*>(vb + ((quad ^ sw) << 3));
            bf16x8 vb1 = *reinterpret_cast<const bf16x8*>(vb + (((quad + 4) ^ sw) << 3));
            #pragma unroll
            for (int i = 0; i < 2; ++i) {
                o[i][n] = __builtin_amdgcn_mfma_f32_16x16x32_bf16(pa[i][0], vb0, o[i][n], 0, 0, 0);
                o[i][n] = __builtin_amdgcn_mfma_f32_16x16x32_bf16(pa[i][1], vb1, o[i][n], 0, 0, 0);
            }
        }
        __builtin_amdgcn_s_setprio(0);
    }

    // l butterfly: sum across the 16 lanes of each quad (cols of the q-row)
    #pragma unroll
    for (int i = 0; i < 2; ++i)
        #pragma unroll
        for (int r = 0; r < 4; ++r) {
            float v = lacc[i][r];
            v += __shfl_xor(v, 1, 64);
            v += __shfl_xor(v, 2, 64);
            v += __shfl_xor(v, 4, 64);
            v += __shfl_xor(v, 8, 64);
            lacc[i][r] = v;
        }

    // epilogue: write UNNORMALIZED partial o (bf16) + partial l (f32)
    unsigned short* Po = kvz ? Po1 : Po0;
    const int b = bh >> 4, h = bh & 15;
    #pragma unroll
    for (int i = 0; i < 2; ++i)
        #pragma unroll
        for (int r = 0; r < 4; ++r) {
            int q = qt * TQ_ + w * 32 + i * 16 + quad * 4 + r;
            if (l15 == 0) Lp[kvz * 65536 + bh * 2048 + q] = lacc[i][r];
            unsigned short* op = Po + ((size_t)b * S_ + q) * D_ + h * DK_;
            #pragma unroll
            for (int n = 0; n < 4; ++n)
                op[n * 16 + l15] = f2bf(o[i][n][r]);
        }
}

// ---------- combine: AO = (Po0 + Po1) / (L0 + L1) ----------
__global__ __launch_bounds__(256)
void comb_k(const unsigned short* __restrict__ Po0, const unsigned short* __restrict__ Po1,
            const float* __restrict__ Lp, unsigned short* __restrict__ AO)
{
    const size_t i4 = (size_t)blockIdx.x * 256 + threadIdx.x;
    const int e = (int)(i4 * 4);
    const int d = e & 1023, s = (e >> 10) & 2047, b = e >> 21;
    const int bh = b * 16 + (d >> 6);
    const float inv = 1.0f / (Lp[bh * 2048 + s] + Lp[65536 + bh * 2048 + s]);
    const ushort4 a = reinterpret_cast<const ushort4*>(Po0)[i4];
    const ushort4 c = reinterpret_cast<const ushort4*>(Po1)[i4];
    ushort4 u;
    u.x = f2bf((bf2f(a.x) + bf2f(c.x)) * inv);
    u.y = f2bf((bf2f(a.y) + bf2f(c.y)) * inv);
    u.z = f2bf((bf2f(a.z) + bf2f(c.z)) * inv);
    u.w = f2bf((bf2f(a.w) + bf2f(c.w)) * inv);
    reinterpret_cast<ushort4*>(AO)[i4] = u;
}

// ---------- reducing LayerNorm: v = P0+P1 (+bias) (+res), then LN (ddof=1) ----------
template<bool HAS_BIAS, bool RES_F32, bool OUT_F32>
__global__ __launch_bounds__(256)
void lnr_k(const unsigned short* __restrict__ P0, const unsigned short* __restrict__ P1,
           const void* __restrict__ res, const float* __restrict__ bias,
           const float* __restrict__ gp, const float* __restrict__ bp,
           void* __restrict__ Out)
{
    const int row = blockIdx.x;
    const int tid = threadIdx.x;
    const int lane = tid & 63, wave = tid >> 6;
    __shared__ float rs[4], rss[4];

    const size_t i4 = (size_t)row * 256 + tid;
    const ushort4 a = reinterpret_cast<const ushort4*>(P0)[i4];
    const ushort4 b = reinterpret_cast<const ushort4*>(P1)[i4];
    float v0 = bf2f(a.x) + bf2f(b.x);
    float v1 = bf2f(a.y) + bf2f(b.y);
    float v2 = bf2f(a.z) + bf2f(b.z);
    float v3 = bf2f(a.w) + bf2f(b.w);
    if (RES_F32) {
        float4 rv = reinterpret_cast<const float4*>(res)[i4];
        v0 += rv.x; v1 += rv.y; v2 += rv.z; v3 += rv.w;
    } else {
        ushort4 rv = reinterpret_cast<const ushort4*>(res)[i4];
        v0 += bf2f(rv.x); v1 += bf2f(rv.y); v2 += bf2f(rv.z); v3 += bf2f(rv.w);
    }
    if (HAS_BIAS) {
        float4 bv = reinterpret_cast<const float4*>(bias)[tid];
        v0 += bv.x; v1 += bv.y; v2 += bv.z; v3 += bv.w;
    }

    float s  = v0 + v1 + v2 + v3;
    float ss = v0*v0 + v1*v1 + v2*v2 + v3*v3;
    s = wave_sum(s);
    ss = wave_sum(ss);
    if (lane == 0) { rs[wave] = s; rss[wave] = ss; }
    __syncthreads();
    const float stot  = rs[0] + rs[1] + rs[2] + rs[3];
    const float sstot = rss[0] + rss[1] + rss[2] + rss[3];
    const float mean = stot / (float)D_;
    const float var  = (sstot - (float)D_ * mean * mean) / (float)(D_ - 1);
    const float scl = gp[0] * rsqrtf(var + EPS_);
    const float be = bp[0];

    float o0 = (v0 - mean) * scl + be;
    float o1 = (v1 - mean) * scl + be;
    float o2 = (v2 - mean) * scl + be;
    float o3 = (v3 - mean) * scl + be;
    if (OUT_F32) {
        reinterpret_cast<float4*>(Out)[i4] = make_float4(o0, o1, o2, o3);
    } else {
        ushort4 o;
        o.x = f2bf(o0); o.y = f2bf(o1); o.z = f2bf(o2); o.w = f2bf(o3);
        reinterpret_cast<ushort4*>(Out)[i4] = o;
    }
}

// ---------- host launch ----------
extern "C" void kernel_launch(void* const* d_in, const int* in_sizes, int n_in,
                              void* d_out, int out_size, void* d_ws, size_t ws_size,
                              hipStream_t stream)
{
    const float* x   = (const float*)d_in[0];
    const float* wq  = (const float*)d_in[2];
    const float* wk  = (const float*)d_in[3];
    const float* wv  = (const float*)d_in[4];
    const float* wo  = (const float*)d_in[5];
    const float* w1  = (const float*)d_in[6];
    const float* b1  = (const float*)d_in[7];
    const float* w2  = (const float*)d_in[8];
    const float* b2  = (const float*)d_in[9];
    const float* g1  = (const float*)d_in[10];
    const float* be1 = (const float*)d_in[11];
    const float* g2  = (const float*)d_in[12];
    const float* be2 = (const float*)d_in[13];

    unsigned short* ws = (unsigned short*)d_ws;
    const size_t need_bytes = 32 * MEGE * 2;           // 64 MB peak
    if (ws_size < need_bytes) {
        fprintf(stderr, "kernel_launch: ws too small (%zu < %zu)\n", ws_size, need_bytes);
    }
    // liveness: Lp (512KB f32) over dead wqt (slot 0) during attn;
    // Po0 over dead xb (slot 12-16); Po1 = AO slot (28-32), combined in place.
    unsigned short* wqt = ws + 0 * MEGE;
    unsigned short* wkt = ws + 1 * MEGE;
    unsigned short* wvt = ws + 2 * MEGE;
    unsigned short* wot = ws + 3 * MEGE;
    unsigned short* w1t = ws + 4 * MEGE;
    unsigned short* w2t = ws + 8 * MEGE;
    unsigned short* xb  = ws + 12 * MEGE;
    unsigned short* Q   = ws + 16 * MEGE;  // Q,K,V contiguous (QKV_STRIDE apart)
    unsigned short* K   = ws + 20 * MEGE;
    unsigned short* V   = ws + 24 * MEGE;
    unsigned short* AO  = ws + 28 * MEGE;
    unsigned short* Po0 = ws + 12 * MEGE;  // kv-half 0 partial (over dead xb)
    unsigned short* Po1 = ws + 28 * MEGE;  // kv-half 1 partial (= AO slot)
    float*          Lp  = (float*)ws;      // [2][32][2048] f32 over dead wqt
    unsigned short* x1  = xb;              // LN1 output (xb dead after combine)
    unsigned short* WP  = ws + 16 * MEGE;  // Wo split-K partials [2][M,D] over dead Q,K
    unsigned short* h1  = ws + 16 * MEGE;  // full [4096,4096] (after LN1)
    unsigned short* FP  = ws + 0 * MEGE;   // FFN-down partials [2][M,D] over dead wqt..w1t

    // 0) fused preprocessing: one launch (4 DxD + w1 + w2 transposes + x convert)
    prep_k<<<dim3(16384), 256, 0, stream>>>(wq, wk, wv, wo, w1, w2, x,
                                            wqt, wkt, wvt, wot, w1t, w2t, xb);

    // 1) fused QKV projection (Q pre-scaled): mg3 16-wave, 192 blocks x 1024 thr
    mg3_k<2, false><<<dim3(3 * D_ / 256, M_ / 256), 1024, 0, stream>>>(
        xb, wqt, nullptr, Q, M_, 3 * D_, D_, D_);

    // 2) flash attention, KV-split=2: 1024 blocks x 256 thr, 4 blocks/CU resident
    fattn_k<<<dim3(B_ * H_ * (S_ / TQ_), 2), 256, 0, stream>>>(Q, K, V, Po0, Po1, Lp);

    // 2b) combine partials -> AO (in place over Po1)
    comb_k<<<dim3(B_ * S_ * D_ / 1024), 256, 0, stream>>>(Po0, Po1, Lp, AO);

    // 3) Wo split-K=2 (mg2 BM=128): 256 blocks, partials -> WP[2][M,D]
    mg2_k<128, 0, false><<<dim3(D_ / 256, M_ / 128, 2), 512, 0, stream>>>(
        AO, wot, nullptr, WP, M_, D_, D_ / 2, D_);

    // 4) LN1 = reduce(WP0+WP1) + x residual -> x1 (bf16)
    lnr_k<false, true, false><<<dim3(M_), 256, 0, stream>>>(
        WP, WP + 4 * MEGE, x, nullptr, g1, be1, x1);

    // 5) FFN-up: mg3 16-wave, 256 blocks x 1024 thr
    mg3_k<0, true><<<dim3(DFF_ / 256, M_ / 256), 1024, 0, stream>>>(
        x1, w1t, b1, h1, M_, DFF_, D_, D_);

    // 6) FFN-down split-K=2 (mg2 BM=128): 256 blocks, partials -> FP[2][M,D]
    mg2_k<128, 0, false><<<dim3(D_ / 256, M_ / 128, 2), 512, 0, stream>>>(
        h1, w2t, nullptr, FP, M_, D_, DFF_ / 2, DFF_);

    // 7) LN2 = reduce(FP0+FP1) + b2 + x1 residual -> fp32 output
    lnr_k<true, false, true><<<dim3(M_), 256, 0, stream>>>(
        FP, FP + 4 * MEGE, x1, b2, g2, be2, d_out);
}

// Round 14
// 329.448 us; speedup vs baseline: 1.0576x; 1.0180x over previous
//
#include <hip/hip_runtime.h>
#include <cstdio>

// Problem constants
constexpr int B_   = 2;
constexpr int S_   = 2048;
constexpr int D_   = 1024;
constexpr int H_   = 16;
constexpr int DFF_ = 4096;
constexpr int DK_  = D_ / H_;   // 64
constexpr int M_   = B_ * S_;   // 4096 tokens
constexpr float EPS_ = 1e-5f;
constexpr size_t MEGE = 1u << 20;          // 1M elems
constexpr size_t QKV_STRIDE = 4 * MEGE;    // Q->K->V slot stride (elems)
constexpr float QSCALE_ = 0.18033688011112042f;  // 0.125 * log2(e): folded into Q

typedef __attribute__((ext_vector_type(8))) short bf16x8;
typedef __attribute__((ext_vector_type(4))) float f32x4;

// ---------- bf16 helpers ----------
__device__ __forceinline__ float bf2f(unsigned int u) {
    return __uint_as_float(u << 16);
}
__device__ __forceinline__ unsigned short f2bf(float f) {          // RTNE
    unsigned int u = __float_as_uint(f);
    unsigned int r = u + 0x7fffu + ((u >> 16) & 1u);
    return (unsigned short)(r >> 16);
}
__device__ __forceinline__ unsigned short f2bf_rz(float f) {       // truncate (P matrix only)
    return (unsigned short)(__float_as_uint(f) >> 16);
}
// 2^x via native v_exp_f32 (NOT __exp2f — glibc macro collision; v_exp_f32 IS exp2).
__device__ __forceinline__ float exp2_fast(float x) {
    float r;
    asm("v_exp_f32 %0, %1" : "=v"(r) : "v"(x));
    return r;
}

// ---------- async global->LDS, 16B per lane ----------
__device__ __forceinline__ void gload_lds16(const unsigned short* g, unsigned short* l) {
    __builtin_amdgcn_global_load_lds(
        (const __attribute__((address_space(1))) unsigned int*)g,
        (__attribute__((address_space(3))) unsigned int*)l, 16, 0, 0);
}

// ---------- fused preprocessing: 6 weight transposes + x convert, ONE launch ----
__device__ __forceinline__ void tr32(const float* __restrict__ W, unsigned short* __restrict__ Wt,
                                     int K, int N, int bx, int by, float* t /*[32*33]*/)
{
    const int tx = threadIdx.x & 31, ty = threadIdx.x >> 5;   // 32 x 8
    const int n0 = bx * 32, k0 = by * 32;
    #pragma unroll
    for (int p = 0; p < 4; ++p)
        t[(ty + p * 8) * 33 + tx] = W[(size_t)(k0 + ty + p * 8) * N + n0 + tx];
    __syncthreads();
    #pragma unroll
    for (int p = 0; p < 4; ++p)
        Wt[(size_t)(n0 + ty + p * 8) * K + k0 + tx] = f2bf(t[tx * 33 + ty + p * 8]);
}

__global__ __launch_bounds__(256)
void prep_k(const float* __restrict__ wq, const float* __restrict__ wk,
            const float* __restrict__ wv, const float* __restrict__ wo,
            const float* __restrict__ w1, const float* __restrict__ w2,
            const float* __restrict__ x,
            unsigned short* __restrict__ wqt, unsigned short* __restrict__ wkt,
            unsigned short* __restrict__ wvt, unsigned short* __restrict__ wot,
            unsigned short* __restrict__ w1t, unsigned short* __restrict__ w2t,
            unsigned short* __restrict__ xb)
{
    __shared__ float t[32 * 33];
    const int bid = blockIdx.x;
    if (bid < 4096) {
        const int z = bid >> 10, rem = bid & 1023;
        const float* W = (z == 0) ? wq : (z == 1) ? wk : (z == 2) ? wv : wo;
        unsigned short* Wt = (z == 0) ? wqt : (z == 1) ? wkt : (z == 2) ? wvt : wot;
        tr32(W, Wt, D_, D_, rem & 31, rem >> 5, t);
    } else if (bid < 8192) {
        const int rem = bid - 4096;
        tr32(w1, w1t, D_, DFF_, rem & 127, rem >> 7, t);
    } else if (bid < 12288) {
        const int rem = bid - 8192;
        tr32(w2, w2t, DFF_, D_, rem & 31, rem >> 5, t);
    } else {
        const int i = (bid - 12288) * 256 + threadIdx.x;
        float4 f = reinterpret_cast<const float4*>(x)[i];
        ushort4 u;
        u.x = f2bf(f.x); u.y = f2bf(f.y); u.z = f2bf(f.z); u.w = f2bf(f.w);
        reinterpret_cast<ushort4*>(xb)[i] = u;
    }
}

// ---------- V transpose: V[b,h,s,dk] -> VT[b,h,dk,s] (bf16) ----------
__global__ __launch_bounds__(256)
void vtr_k(const unsigned short* __restrict__ V, unsigned short* __restrict__ VT)
{
    __shared__ unsigned short t[32][33];
    const int bh = blockIdx.z;
    const int s0 = blockIdx.y * 32;
    const int d0 = blockIdx.x * 32;
    const int tx = threadIdx.x & 31, ty = threadIdx.x >> 5;
    const unsigned short* vb = V + (size_t)bh * S_ * DK_;
    unsigned short* vt = VT + (size_t)bh * DK_ * S_;
    #pragma unroll
    for (int p = 0; p < 4; ++p)
        t[ty + p * 8][tx] = vb[(size_t)(s0 + ty + p * 8) * DK_ + d0 + tx];
    __syncthreads();
    #pragma unroll
    for (int p = 0; p < 4; ++p)
        vt[(size_t)(d0 + ty + p * 8) * S_ + s0 + tx] = t[tx][ty + p * 8];
}

// ---------- mg3: 16-wave 256x256 MFMA GEMM (QKV / FFN-up) ----------
template<int OMODE, bool RELU>
__global__ __launch_bounds__(1024, 1)
void mg3_k(const unsigned short* __restrict__ A,
           const unsigned short* __restrict__ Bt,
           const float* __restrict__ bias,
           unsigned short* __restrict__ C,
           int M, int N, int K, int Kld)
{
    __shared__ __align__(16) unsigned short As[2][256 * 64];
    __shared__ __align__(16) unsigned short Bs[2][256 * 64];

    const int tid = threadIdx.x;
    const int w = tid >> 6, lane = tid & 63;
    const int l15 = lane & 15, quad = lane >> 4;
    const int wm = w >> 2, wn = w & 3;              // 4M x 4N wave grid
    const int m0 = blockIdx.y * 256, n0 = blockIdx.x * 256;
    const int NT = K >> 6;

    const int srow = lane >> 3;                     // DMA row within 8-row group
    const int schk = (lane & 7) ^ srow;             // pre-swizzled source chunk
    const int rsw  = l15 & 7;                       // read-side swizzle key

    f32x4 acc[4][4];
    #pragma unroll
    for (int i = 0; i < 4; ++i)
        #pragma unroll
        for (int j = 0; j < 4; ++j) acc[i][j] = (f32x4){0.f, 0.f, 0.f, 0.f};

    auto stageAB = [&](int tile) {
        if (tile >= NT) return;
        const int buf = tile & 1;
        const int k0 = tile * 64;
        #pragma unroll
        for (int g = 0; g < 2; ++g) {
            const int r = w * 16 + g * 8;
            gload_lds16(A + (size_t)(m0 + r + srow) * Kld + k0 + schk * 8, &As[buf][r * 64]);
        }
        #pragma unroll
        for (int g = 0; g < 2; ++g) {
            const int r = w * 16 + g * 8;
            gload_lds16(Bt + (size_t)(n0 + r + srow) * Kld + k0 + schk * 8, &Bs[buf][r * 64]);
        }
    };

    bf16x8 a[4], b[4];
    auto rd = [&](int buf, int h) {
        #pragma unroll
        for (int i = 0; i < 4; ++i) {
            const unsigned short* rp = &As[buf][(wm * 64 + i * 16 + l15) * 64];
            a[i] = *reinterpret_cast<const bf16x8*>(rp + (((quad + 4 * h) ^ rsw) << 3));
        }
        #pragma unroll
        for (int j = 0; j < 4; ++j) {
            const unsigned short* rp = &Bs[buf][(wn * 64 + j * 16 + l15) * 64];
            b[j] = *reinterpret_cast<const bf16x8*>(rp + (((quad + 4 * h) ^ rsw) << 3));
        }
    };
    auto mm16 = [&]() {
        __builtin_amdgcn_s_setprio(1);
        #pragma unroll
        for (int i = 0; i < 4; ++i)
            #pragma unroll
            for (int j = 0; j < 4; ++j)
                acc[i][j] = __builtin_amdgcn_mfma_f32_16x16x32_bf16(a[i], b[j], acc[i][j], 0, 0, 0);
        __builtin_amdgcn_s_setprio(0);
    };

    stageAB(0);

    for (int t = 0; t < NT; ++t) {
        const int cur = t & 1;
        asm volatile("s_waitcnt vmcnt(0)" ::: "memory");  // drains tile t (issued 1 tile ago)
        __builtin_amdgcn_s_barrier();
        stageAB(t + 1);
        rd(cur, 0);
        __builtin_amdgcn_s_barrier();
        asm volatile("s_waitcnt lgkmcnt(0)" ::: "memory");
        mm16();
        rd(cur, 1);
        __builtin_amdgcn_s_barrier();
        asm volatile("s_waitcnt lgkmcnt(0)" ::: "memory");
        mm16();
    }

    #pragma unroll
    for (int i = 0; i < 4; ++i)
        #pragma unroll
        for (int r = 0; r < 4; ++r) {
            const int m = m0 + wm * 64 + i * 16 + quad * 4 + r;
            #pragma unroll
            for (int j = 0; j < 4; ++j) {
                const int n = n0 + wn * 64 + j * 16 + l15;
                float v = acc[i][j][r];
                if (bias) v += bias[n];
                if (RELU) v = fmaxf(v, 0.0f);
                size_t o;
                if (OMODE == 2) {
                    int mat = n >> 10, nn = n & 1023;
                    int bb = m >> 11, s = m & 2047;
                    int h = nn >> 6, dk = nn & 63;
                    if (mat == 0) v *= QSCALE_;   // fold softmax scale+log2e into Q
                    o = (size_t)mat * QKV_STRIDE + (((size_t)bb * H_ + h) * S_ + s) * DK_ + dk;
                } else {
                    o = (size_t)m * N + n;
                }
                C[o] = f2bf(v);
            }
        }
}

// ---------- phased MFMA GEMM (mg2, BM=128 path): Wo / FFN-down split-K ----------
template<int BM, int OMODE, bool RELU>
__global__ __launch_bounds__(512, 2)
void mg2_k(const unsigned short* __restrict__ A,
           const unsigned short* __restrict__ Bt,
           const float* __restrict__ bias,
           unsigned short* __restrict__ C,
           int M, int N, int K, int Kld)
{
    constexpr int MI  = BM / 64;
    constexpr int AMH = (BM == 128) ? 2 : 1;
    __shared__ __align__(16) unsigned short As[2][BM * 64];
    __shared__ __align__(16) unsigned short Bs[2][256 * 64];

    const int z = blockIdx.z;
    A  += (size_t)z * K;
    Bt += (size_t)z * K;
    C  += (size_t)z * ((size_t)M * N);

    const int tid  = threadIdx.x;
    const int w    = tid >> 6, lane = tid & 63;
    const int l15  = lane & 15, quad = lane >> 4;
    const int wm   = w >> 2, wn = w & 3;
    const int m0   = blockIdx.y * BM, n0 = blockIdx.x * 256;
    const int NT   = K >> 6;

    const int srow = lane >> 3;
    const int schk = (lane & 7) ^ srow;
    const int rsw  = l15 & 7;

    f32x4 acc[2][MI][2][2];
    #pragma unroll
    for (int mh = 0; mh < 2; ++mh)
        #pragma unroll
        for (int mi = 0; mi < MI; ++mi)
            #pragma unroll
            for (int nh = 0; nh < 2; ++nh)
                #pragma unroll
                for (int nj = 0; nj < 2; ++nj)
                    acc[mh][mi][nh][nj] = (f32x4){0.f, 0.f, 0.f, 0.f};

    bf16x8 aA[AMH][MI][2];
    bf16x8 b0[2][2], b1[2][2];

    auto stage = [&](int tile, int type) {
        if (tile >= NT) return;
        const int buf = tile & 1;
        unsigned short* dst; const unsigned short* src; int r0;
        if (BM == 256) {
            if      (type == 0) { dst = &As[buf][0];        src = A;  r0 = m0; }
            else if (type == 1) { dst = &Bs[buf][0];        src = Bt; r0 = n0; }
            else if (type == 2) { dst = &Bs[buf][128 * 64]; src = Bt; r0 = n0 + 128; }
            else                { dst = &As[buf][128 * 64]; src = A;  r0 = m0 + 128; }
        } else {
            if      (type == 0) { dst = &Bs[buf][0];        src = Bt; r0 = n0; }
            else if (type == 1) { dst = &As[buf][0];        src = A;  r0 = m0; }
            else                { dst = &Bs[buf][128 * 64]; src = Bt; r0 = n0 + 128; }
        }
        const int k0 = tile * 64;
        #pragma unroll
        for (int g = 0; g < 2; ++g) {
            const int r = w * 16 + g * 8 + srow;
            gload_lds16(src + (size_t)(r0 + r) * Kld + k0 + schk * 8,
                        dst + (w * 16 + g * 8) * 64);
        }
    };
    auto rdA = [&](int buf, int mh, int amh) {
        const unsigned short* base = &As[buf][(BM == 256 && mh) ? 128 * 64 : 0];
        #pragma unroll
        for (int mi = 0; mi < MI; ++mi) {
            const int row = (BM == 256) ? (wm * 64 + mi * 16 + l15)
                                        : (wm * 64 + mh * 32 + mi * 16 + l15);
            const unsigned short* rp = base + row * 64;
            aA[amh][mi][0] = *reinterpret_cast<const bf16x8*>(rp + ((quad    ) ^ rsw) * 8);
            aA[amh][mi][1] = *reinterpret_cast<const bf16x8*>(rp + ((quad + 4) ^ rsw) * 8);
        }
    };
    auto rdB = [&](int buf, int nh, bf16x8 (&b)[2][2]) {
        const unsigned short* base = &Bs[buf][nh ? 128 * 64 : 0];
        #pragma unroll
        for (int nj = 0; nj < 2; ++nj) {
            const int row = wn * 32 + nj * 16 + l15;
            const unsigned short* rp = base + row * 64;
            b[nj][0] = *reinterpret_cast<const bf16x8*>(rp + ((quad    ) ^ rsw) * 8);
            b[nj][1] = *reinterpret_cast<const bf16x8*>(rp + ((quad + 4) ^ rsw) * 8);
        }
    };
    auto mm = [&](int mh, int amh, int nh, bf16x8 (&b)[2][2]) {
        __builtin_amdgcn_s_setprio(1);
        #pragma unroll
        for (int mi = 0; mi < MI; ++mi)
            #pragma unroll
            for (int nj = 0; nj < 2; ++nj) {
                acc[mh][mi][nh][nj] = __builtin_amdgcn_mfma_f32_16x16x32_bf16(
                    aA[amh][mi][0], b[nj][0], acc[mh][mi][nh][nj], 0, 0, 0);
                acc[mh][mi][nh][nj] = __builtin_amdgcn_mfma_f32_16x16x32_bf16(
                    aA[amh][mi][1], b[nj][1], acc[mh][mi][nh][nj], 0, 0, 0);
            }
        __builtin_amdgcn_s_setprio(0);
    };

    if (BM == 256) {
        stage(0, 0); stage(0, 1); stage(0, 2); stage(0, 3);
        stage(1, 0); stage(1, 1); stage(1, 2);
    } else {
        stage(0, 0); stage(0, 1); stage(0, 2);
        stage(1, 0); stage(1, 1);
    }

    for (int t = 0; t < NT; ++t) {
        const int cur = t & 1;
        if (t == NT - 1)    asm volatile("s_waitcnt vmcnt(0)" ::: "memory");
        else if (BM == 256) asm volatile("s_waitcnt vmcnt(6)" ::: "memory");
        else                asm volatile("s_waitcnt vmcnt(4)" ::: "memory");
        __builtin_amdgcn_s_barrier();

        if (BM == 256) {
            rdA(cur, 0, 0); rdB(cur, 0, b0); stage(t + 1, 3);
            __builtin_amdgcn_s_barrier();
            asm volatile("s_waitcnt lgkmcnt(0)" ::: "memory");
            mm(0, 0, 0, b0);
            __builtin_amdgcn_s_barrier();
            rdB(cur, 1, b1); stage(t + 2, 0);
            __builtin_amdgcn_s_barrier();
            asm volatile("s_waitcnt lgkmcnt(0)" ::: "memory");
            mm(0, 0, 1, b1);
            __builtin_amdgcn_s_barrier();
            rdA(cur, 1, 0); stage(t + 2, 1);
            __builtin_amdgcn_s_barrier();
            asm volatile("s_waitcnt lgkmcnt(0)" ::: "memory");
            mm(1, 0, 0, b0);
            __builtin_amdgcn_s_barrier();
            stage(t + 2, 2);
            __builtin_amdgcn_s_barrier();
            asm volatile("s_waitcnt lgkmcnt(0)" ::: "memory");
            mm(1, 0, 1, b1);
        } else {
            rdA(cur, 0, 0); rdA(cur, 1, 1); rdB(cur, 0, b0); stage(t + 1, 2);
            __builtin_amdgcn_s_barrier();
            asm volatile("s_waitcnt lgkmcnt(0)" ::: "memory");
            mm(0, 0, 0, b0); mm(1, 1, 0, b0);
            __builtin_amdgcn_s_barrier();
            rdB(cur, 1, b1); stage(t + 2, 0); stage(t + 2, 1);
            __builtin_amdgcn_s_barrier();
            asm volatile("s_waitcnt lgkmcnt(0)" ::: "memory");
            mm(0, 0, 1, b1); mm(1, 1, 1, b1);
        }
    }

    #pragma unroll
    for (int mh = 0; mh < 2; ++mh)
        #pragma unroll
        for (int mi = 0; mi < MI; ++mi) {
            const int mrow = (BM == 256) ? (mh * 128 + wm * 64 + mi * 16)
                                         : (wm * 64 + mh * 32 + mi * 16);
            #pragma unroll
            for (int r = 0; r < 4; ++r) {
                const int m = m0 + mrow + quad * 4 + r;
                #pragma unroll
                for (int nh = 0; nh < 2; ++nh)
                    #pragma unroll
                    for (int nj = 0; nj < 2; ++nj) {
                        const int n = n0 + nh * 128 + wn * 32 + nj * 16 + l15;
                        float v = acc[mh][mi][nh][nj][r];
                        if (bias) v += bias[n];
                        if (RELU) v = fmaxf(v, 0.0f);
                        size_t o;
                        if (OMODE == 2) {
                            int mat = n >> 10, nn = n & 1023;
                            int b = m >> 11, s = m & 2047;
                            int h = nn >> 6, dk = nn & 63;
                            if (mat == 0) v *= QSCALE_;
                            o = (size_t)mat * QKV_STRIDE + (((size_t)b * H_ + h) * S_ + s) * DK_ + dk;
                        } else {
                            o = (size_t)m * N + n;
                        }
                        C[o] = f2bf(v);
                    }
            }
        }
}

// ---------- wave reduction ----------
__device__ __forceinline__ float wave_sum(float v) {
    #pragma unroll
    for (int off = 32; off > 0; off >>= 1) v += __shfl_down(v, off, 64);
    return v;
}

// ---------- flash attention v8: 8 waves x 16 q, V pre-transposed (DMA-only) ----
// v5 (R8, 56us) is the verified base; its VALU block is the per-tile register
// V-transpose. v8: (a) V^T staged via global_load_lds from pre-transposed VT
// (waves 0-3), K staged by waves 4-7 — zero VALU staging; (b) denominator via
// register lacc + 16-lane butterfly (no ones-rows, -2 MFMA/tile, -4KB LDS);
// (c) in-kernel normalize -> AO direct (comb_k eliminated).
constexpr int TQ_ = 128;
constexpr int TK_ = 64;
constexpr int NT_ = S_ / TK_;  // 32 kv tiles

__global__ __launch_bounds__(512)
void fattn_k(const unsigned short* __restrict__ Qm, const unsigned short* __restrict__ Km,
             const unsigned short* __restrict__ VT, unsigned short* __restrict__ O)
{
    const int bh  = blockIdx.x >> 4;     // 16 q-tiles per (b,h)
    const int qt  = blockIdx.x & 15;
    const int tid = threadIdx.x;
    const int w = tid >> 6, lane = tid & 63;
    const int quad = lane >> 4, l15 = lane & 15;
    const int sw = l15 & 7;                          // read-side swizzle key

    __shared__ __align__(16) unsigned short Ks[2][TK_][64];   // 16 KB  K tile [k][d]
    __shared__ __align__(16) unsigned short Vs[2][DK_][64];   // 16 KB  V^T tile [d][k]
    __shared__ __align__(16) unsigned short Ps[8][16][64];    // 16 KB  per-wave P

    // Q frags: wave w owns q rows qt*128 + w*16 + [0,16)
    bf16x8 qf0, qf1;
    {
        const unsigned short* qp = Qm + ((size_t)bh * S_ + qt * TQ_ + w * 16 + l15) * DK_;
        qf0 = *reinterpret_cast<const bf16x8*>(qp + quad * 8);
        qf1 = *reinterpret_cast<const bf16x8*>(qp + 32 + quad * 8);
    }

    f32x4 o[4];
    float lacc[4];
    #pragma unroll
    for (int n = 0; n < 4; ++n) o[n] = (f32x4){0.f, 0.f, 0.f, 0.f};
    #pragma unroll
    for (int r = 0; r < 4; ++r) lacc[r] = 0.f;

    const unsigned short* kg0 = Km + (size_t)bh * S_ * DK_;
    const unsigned short* vt0 = VT + (size_t)bh * DK_ * S_;
    const int srow = lane >> 3;               // DMA: lane -> row within 8-row group
    const int schk = (lane & 7) ^ srow;       // pre-swizzled source chunk

    // K tile DMA (waves 4-7): rows [(w-4)*16, +16) of [k][d]
    auto stageK = [&](int t, int buf) {
        const unsigned short* src = kg0 + (size_t)t * TK_ * DK_;
        const int wk = w - 4;
        #pragma unroll
        for (int g = 0; g < 2; ++g) {
            const int r0 = wk * 16 + g * 8;
            gload_lds16(src + (size_t)(r0 + srow) * DK_ + schk * 8, &Ks[buf][r0][0]);
        }
    };
    // V^T tile DMA (waves 0-3): rows [w*16, +16) of [d][k]; global row stride S_
    auto stageV = [&](int t, int buf) {
        const unsigned short* src = vt0 + t * TK_;
        #pragma unroll
        for (int g = 0; g < 2; ++g) {
            const int r0 = w * 16 + g * 8;
            gload_lds16(src + (size_t)(r0 + srow) * S_ + schk * 8, &Vs[buf][r0][0]);
        }
    };

    // prologue: tile 0 staged (pure DMA, both halves)
    if (w >= 4) stageK(0, 0); else stageV(0, 0);

    for (int t = 0; t < NT_; ++t) {
        const int cur = t & 1, nxt = cur ^ 1;
        __syncthreads();   // per-wave vmcnt drain + CU-wide LDS ordering

        const bool hn = (t + 1 < NT_);
        if (hn) { if (w >= 4) stageK(t + 1, nxt); else stageV(t + 1, nxt); }

        // QK^T: 8 MFMA
        f32x4 s[4];
        __builtin_amdgcn_s_setprio(1);
        #pragma unroll
        for (int n = 0; n < 4; ++n) {
            const unsigned short* kp = &Ks[cur][n * 16 + l15][0];
            bf16x8 b0 = *reinterpret_cast<const bf16x8*>(kp + ((quad ^ sw) << 3));
            bf16x8 b1 = *reinterpret_cast<const bf16x8*>(kp + (((quad + 4) ^ sw) << 3));
            f32x4 a2 = (f32x4){0.f, 0.f, 0.f, 0.f};
            a2 = __builtin_amdgcn_mfma_f32_16x16x32_bf16(qf0, b0, a2, 0, 0, 0);
            a2 = __builtin_amdgcn_mfma_f32_16x16x32_bf16(qf1, b1, a2, 0, 0, 0);
            s[n] = a2;
        }
        __builtin_amdgcn_s_setprio(0);

        // softmax: P = exp2(s) (Q pre-scaled) + l accumulate + P write
        #pragma unroll
        for (int r = 0; r < 4; ++r) {
            float p0 = exp2_fast(s[0][r]);
            float p1 = exp2_fast(s[1][r]);
            float p2 = exp2_fast(s[2][r]);
            float p3 = exp2_fast(s[3][r]);
            lacc[r] += (p0 + p1) + (p2 + p3);
            ushort4 pk;
            pk.x = f2bf_rz(p0); pk.y = f2bf_rz(p1);
            pk.z = f2bf_rz(p2); pk.w = f2bf_rz(p3);
            const int R = quad * 4 + r;
            *reinterpret_cast<ushort4*>(
                reinterpret_cast<char*>(&Ps[w][R][0]) +
                ((((l15 >> 1) ^ (R & 7)) << 4) + ((l15 & 1) << 3))) = pk;
        }

        // PV: 8 MFMA over pre-transposed V
        bf16x8 pa0, pa1;
        {
            const unsigned short* pp = &Ps[w][l15][0];
            pa0 = *reinterpret_cast<const bf16x8*>(pp + ((quad ^ sw) << 3));
            pa1 = *reinterpret_cast<const bf16x8*>(pp + (((quad + 4) ^ sw) << 3));
        }
        __builtin_amdgcn_s_setprio(1);
        #pragma unroll
        for (int n = 0; n < 4; ++n) {
            const unsigned short* vb = &Vs[cur][n * 16 + l15][0];
            bf16x8 vb0 = *reinterpret_cast<const bf16x8*>(vb + ((quad ^ sw) << 3));
            bf16x8 vb1 = *reinterpret_cast<const bf16x8*>(vb + (((quad + 4) ^ sw) << 3));
            o[n] = __builtin_amdgcn_mfma_f32_16x16x32_bf16(pa0, vb0, o[n], 0, 0, 0);
            o[n] = __builtin_amdgcn_mfma_f32_16x16x32_bf16(pa1, vb1, o[n], 0, 0, 0);
        }
        __builtin_amdgcn_s_setprio(0);
    }

    // l butterfly: sum across the 16 lanes of each quad-group
    #pragma unroll
    for (int r = 0; r < 4; ++r) {
        float v = lacc[r];
        v += __shfl_xor(v, 1, 64);
        v += __shfl_xor(v, 2, 64);
        v += __shfl_xor(v, 4, 64);
        v += __shfl_xor(v, 8, 64);
        lacc[r] = v;
    }

    // epilogue: normalized write
    const int b = bh >> 4, h = bh & 15;
    #pragma unroll
    for (int r = 0; r < 4; ++r) {
        const float inv = 1.0f / lacc[r];
        const int q = qt * TQ_ + w * 16 + quad * 4 + r;
        unsigned short* op = O + ((size_t)b * S_ + q) * D_ + h * DK_;
        #pragma unroll
        for (int n = 0; n < 4; ++n)
            op[n * 16 + l15] = f2bf(o[n][r] * inv);
    }
}

// ---------- reducing LayerNorm: v = P0+P1 (+bias) (+res), then LN (ddof=1) ----------
template<bool HAS_BIAS, bool RES_F32, bool OUT_F32>
__global__ __launch_bounds__(256)
void lnr_k(const unsigned short* __restrict__ P0, const unsigned short* __restrict__ P1,
           const void* __restrict__ res, const float* __restrict__ bias,
           const float* __restrict__ gp, const float* __restrict__ bp,
           void* __restrict__ Out)
{
    const int row = blockIdx.x;
    const int tid = threadIdx.x;
    const int lane = tid & 63, wave = tid >> 6;
    __shared__ float rs[4], rss[4];

    const size_t i4 = (size_t)row * 256 + tid;
    const ushort4 a = reinterpret_cast<const ushort4*>(P0)[i4];
    const ushort4 b = reinterpret_cast<const ushort4*>(P1)[i4];
    float v0 = bf2f(a.x) + bf2f(b.x);
    float v1 = bf2f(a.y) + bf2f(b.y);
    float v2 = bf2f(a.z) + bf2f(b.z);
    float v3 = bf2f(a.w) + bf2f(b.w);
    if (RES_F32) {
        float4 rv = reinterpret_cast<const float4*>(res)[i4];
        v0 += rv.x; v1 += rv.y; v2 += rv.z; v3 += rv.w;
    } else {
        ushort4 rv = reinterpret_cast<const ushort4*>(res)[i4];
        v0 += bf2f(rv.x); v1 += bf2f(rv.y); v2 += bf2f(rv.z); v3 += bf2f(rv.w);
    }
    if (HAS_BIAS) {
        float4 bv = reinterpret_cast<const float4*>(bias)[tid];
        v0 += bv.x; v1 += bv.y; v2 += bv.z; v3 += bv.w;
    }

    float s  = v0 + v1 + v2 + v3;
    float ss = v0*v0 + v1*v1 + v2*v2 + v3*v3;
    s = wave_sum(s);
    ss = wave_sum(ss);
    if (lane == 0) { rs[wave] = s; rss[wave] = ss; }
    __syncthreads();
    const float stot  = rs[0] + rs[1] + rs[2] + rs[3];
    const float sstot = rss[0] + rss[1] + rss[2] + rss[3];
    const float mean = stot / (float)D_;
    const float var  = (sstot - (float)D_ * mean * mean) / (float)(D_ - 1);
    const float scl = gp[0] * rsqrtf(var + EPS_);
    const float be = bp[0];

    float o0 = (v0 - mean) * scl + be;
    float o1 = (v1 - mean) * scl + be;
    float o2 = (v2 - mean) * scl + be;
    float o3 = (v3 - mean) * scl + be;
    if (OUT_F32) {
        reinterpret_cast<float4*>(Out)[i4] = make_float4(o0, o1, o2, o3);
    } else {
        ushort4 o;
        o.x = f2bf(o0); o.y = f2bf(o1); o.z = f2bf(o2); o.w = f2bf(o3);
        reinterpret_cast<ushort4*>(Out)[i4] = o;
    }
}

// ---------- host launch ----------
extern "C" void kernel_launch(void* const* d_in, const int* in_sizes, int n_in,
                              void* d_out, int out_size, void* d_ws, size_t ws_size,
                              hipStream_t stream)
{
    const float* x   = (const float*)d_in[0];
    const float* wq  = (const float*)d_in[2];
    const float* wk  = (const float*)d_in[3];
    const float* wv  = (const float*)d_in[4];
    const float* wo  = (const float*)d_in[5];
    const float* w1  = (const float*)d_in[6];
    const float* b1  = (const float*)d_in[7];
    const float* w2  = (const float*)d_in[8];
    const float* b2  = (const float*)d_in[9];
    const float* g1  = (const float*)d_in[10];
    const float* be1 = (const float*)d_in[11];
    const float* g2  = (const float*)d_in[12];
    const float* be2 = (const float*)d_in[13];

    unsigned short* ws = (unsigned short*)d_ws;
    const size_t need_bytes = 32 * MEGE * 2;           // 64 MB peak
    if (ws_size < need_bytes) {
        fprintf(stderr, "kernel_launch: ws too small (%zu < %zu)\n", ws_size, need_bytes);
    }
    unsigned short* wqt = ws + 0 * MEGE;
    unsigned short* wkt = ws + 1 * MEGE;
    unsigned short* wvt = ws + 2 * MEGE;
    unsigned short* wot = ws + 3 * MEGE;
    unsigned short* w1t = ws + 4 * MEGE;
    unsigned short* w2t = ws + 8 * MEGE;
    unsigned short* xb  = ws + 12 * MEGE;
    unsigned short* Q   = ws + 16 * MEGE;  // Q,K,V contiguous (QKV_STRIDE apart)
    unsigned short* K   = ws + 20 * MEGE;
    unsigned short* V   = ws + 24 * MEGE;
    unsigned short* AO  = ws + 28 * MEGE;
    unsigned short* VTm = ws + 12 * MEGE;  // V^T [b,h,dk,s] over dead xb (4 MEGE)
    unsigned short* x1  = xb;              // LN1 output (VT dead after fattn)
    unsigned short* WP  = ws + 16 * MEGE;  // Wo split-K partials [2][M,D] over dead Q,K
    unsigned short* h1  = ws + 16 * MEGE;  // full [4096,4096] (after LN1)
    unsigned short* FP  = ws + 0 * MEGE;   // FFN-down partials [2][M,D] over dead wqt..w1t

    // 0) fused preprocessing: one launch (4 DxD + w1 + w2 transposes + x convert)
    prep_k<<<dim3(16384), 256, 0, stream>>>(wq, wk, wv, wo, w1, w2, x,
                                            wqt, wkt, wvt, wot, w1t, w2t, xb);

    // 1) fused QKV projection (Q pre-scaled): mg3 16-wave, 192 blocks x 1024 thr
    mg3_k<2, false><<<dim3(3 * D_ / 256, M_ / 256), 1024, 0, stream>>>(
        xb, wqt, nullptr, Q, M_, 3 * D_, D_, D_);

    // 1b) V transpose: V[b,h,s,dk] -> VT[b,h,dk,s]
    vtr_k<<<dim3(DK_ / 32, S_ / 32, B_ * H_), 256, 0, stream>>>(V, VTm);

    // 2) flash attention: 512 blocks x 512 thr (8 waves, 16 q each), DMA-only staging
    fattn_k<<<dim3(B_ * H_ * (S_ / TQ_)), 512, 0, stream>>>(Q, K, VTm, AO);

    // 3) Wo split-K=2 (mg2 BM=128): 256 blocks, partials -> WP[2][M,D]
    mg2_k<128, 0, false><<<dim3(D_ / 256, M_ / 128, 2), 512, 0, stream>>>(
        AO, wot, nullptr, WP, M_, D_, D_ / 2, D_);

    // 4) LN1 = reduce(WP0+WP1) + x residual -> x1 (bf16)
    lnr_k<false, true, false><<<dim3(M_), 256, 0, stream>>>(
        WP, WP + 4 * MEGE, x, nullptr, g1, be1, x1);

    // 5) FFN-up: mg3 16-wave, 256 blocks x 1024 thr
    mg3_k<0, true><<<dim3(DFF_ / 256, M_ / 256), 1024, 0, stream>>>(
        x1, w1t, b1, h1, M_, DFF_, D_, D_);

    // 6) FFN-down split-K=2 (mg2 BM=128): 256 blocks, partials -> FP[2][M,D]
    mg2_k<128, 0, false><<<dim3(D_ / 256, M_ / 128, 2), 512, 0, stream>>>(
        h1, w2t, nullptr, FP, M_, D_, DFF_ / 2, DFF_);

    // 7) LN2 = reduce(FP0+FP1) + b2 + x1 residual -> fp32 output
    lnr_k<true, false, true><<<dim3(M_), 256, 0, stream>>>(
        FP, FP + 4 * MEGE, x1, b2, g2, be2, d_out);
}